// Round 7
// baseline (1482.795 us; speedup 1.0000x reference)
//
#include <hip/hip_runtime.h>

typedef unsigned short u16;
typedef __attribute__((ext_vector_type(8))) short bf16x8;
typedef __attribute__((ext_vector_type(4))) float f32x4;

#define BB   16
#define LL   511
#define SS   512
#define DD   1024
#define HIDD 512
#define DFFF 2048
#define NHH  4
#define HDD  256
#define MTOK (BB*SS)   // 8192

__device__ __forceinline__ float b2f(u16 u){ return __uint_as_float(((unsigned)u)<<16); }
__device__ __forceinline__ u16 f2b(float f){
    unsigned x = __float_as_uint(f);
    return (u16)((x + 0x7fffu + ((x>>16)&1u)) >> 16);   // RNE
}
__device__ __forceinline__ float ldin(const void* p, size_t i, int f){
    return f ? ((const float*)p)[i] : b2f(((const u16*)p)[i]);
}
__device__ __forceinline__ void gload_lds16(const void* g, void* l){
    __builtin_amdgcn_global_load_lds((const __attribute__((address_space(1))) unsigned*)g,
                                     (__attribute__((address_space(3))) unsigned*)l, 16, 0, 0);
}

// ---------------- dtype detect ----------------
__global__ void detect_kernel(const u16* __restrict__ lnw, int* __restrict__ flag){
    if (threadIdx.x == 0 && blockIdx.x == 0) flag[0] = (lnw[0] == 0x3F80) ? 0 : 1;
}

// ---------------- weight (+bias) conversion into bf16 scratch ----------------
__global__ void wconv_kernel(const void* __restrict__ w, size_t woff,
                             const void* __restrict__ b, size_t boff,
                             u16* __restrict__ dw, u16* __restrict__ db,
                             int nw, int nb, const int* __restrict__ flag){
    const int f = flag[0];
    const int idx = blockIdx.x*256 + threadIdx.x;
    const int stride = gridDim.x * 256;
    if (f){
        const float* wf = (const float*)w + woff;
        const float* bf = (const float*)b + boff;
        for (int i = idx*4; i < nw; i += stride*4){
            const float4 v = *(const float4*)&wf[i];
            ushort4 o; o.x=f2b(v.x); o.y=f2b(v.y); o.z=f2b(v.z); o.w=f2b(v.w);
            *(ushort4*)&dw[i] = o;
        }
        for (int i = idx*4; i < nb; i += stride*4){
            const float4 v = *(const float4*)&bf[i];
            ushort4 o; o.x=f2b(v.x); o.y=f2b(v.y); o.z=f2b(v.z); o.w=f2b(v.w);
            *(ushort4*)&db[i] = o;
        }
    } else {
        const u16* wu = (const u16*)w + woff;
        const u16* bu = (const u16*)b + boff;
        for (int i = idx*4; i < nw; i += stride*4) *(ushort4*)&dw[i] = *(const ushort4*)&wu[i];
        for (int i = idx*4; i < nb; i += stride*4) *(ushort4*)&db[i] = *(const ushort4*)&bu[i];
    }
}

// batched variant: 8 conversion jobs in ONE dispatch (blockIdx.y = job)
struct WJob  { const void* w; const void* b; u16* dw; u16* db; int nw; int nb; };
struct WJobs { WJob j[8]; };
__global__ void wconv8_kernel(WJobs jobs, const int* __restrict__ flag){
    const int f = flag[0];
    const WJob J = jobs.j[blockIdx.y];
    const int idx = blockIdx.x*256 + threadIdx.x;
    const int stride = gridDim.x * 256;
    if (f){
        const float* wf = (const float*)J.w;
        const float* bf = (const float*)J.b;
        for (int i = idx*4; i < J.nw; i += stride*4){
            const float4 v = *(const float4*)&wf[i];
            ushort4 o; o.x=f2b(v.x); o.y=f2b(v.y); o.z=f2b(v.z); o.w=f2b(v.w);
            *(ushort4*)&J.dw[i] = o;
        }
        for (int i = idx*4; i < J.nb; i += stride*4){
            const float4 v = *(const float4*)&bf[i];
            ushort4 o; o.x=f2b(v.x); o.y=f2b(v.y); o.z=f2b(v.z); o.w=f2b(v.w);
            *(ushort4*)&J.db[i] = o;
        }
    } else {
        const u16* wu = (const u16*)J.w;
        const u16* bu = (const u16*)J.b;
        for (int i = idx*4; i < J.nw; i += stride*4) *(ushort4*)&J.dw[i] = *(const ushort4*)&wu[i];
        for (int i = idx*4; i < J.nb; i += stride*4) *(ushort4*)&J.db[i] = *(const ushort4*)&bu[i];
    }
}

// ---------------- positional encoding ----------------
__global__ void pe_kernel(float* __restrict__ pe){
    const int i = blockIdx.x*256 + threadIdx.x;       // < 512*512
    const int s = i >> 9, c = i & 511;
    const float div = expf(-(float)(c & ~1) * (logf(10000.0f)/512.0f));
    const float ang = (float)s * div;
    pe[i] = (c & 1) ? cosf(ang) : sinf(ang);
}

// ---------------- input proj stage 1 ----------------
__global__ void inp_u_kernel(const void* __restrict__ bos, const void* __restrict__ target,
                             const void* __restrict__ w1, const void* __restrict__ b1,
                             u16* __restrict__ U, const int* __restrict__ flag){
    const int f = flag[0];
    const int i = blockIdx.x*256 + threadIdx.x;       // < MTOK*HIDD
    const int m = i >> 9, c = i & 511;
    const int b = m >> 9, s = m & 511;
    const float ts = (s == 0) ? ldin(bos, 0, f) : ldin(target, b*LL + s - 1, f);
    float v = ts * ldin(w1, c, f) + ldin(b1, c, f);
    U[i] = f2b(v >= 0.f ? v : 0.01f*v);
}

// ---------------- concat ----------------
__global__ void concat_kernel(const void* __restrict__ gs, const void* __restrict__ prev,
                              const void* __restrict__ cur, u16* __restrict__ tgt,
                              u16* __restrict__ mem, const int* __restrict__ flag){
    const int f = flag[0];
    const int i = blockIdx.x*256 + threadIdx.x;       // < MTOK*DD
    const int m = i >> 10, c = i & 1023;
    if (c < 512){
        mem[i] = f2b(ldin(gs, (size_t)m*512 + c, f));
    } else {
        const float pc = (c < 768) ? ldin(prev, (m>>9)*256 + (c-512), f)
                                   : ldin(cur,  (m>>9)*256 + (c-768), f);
        const u16 pb = f2b(pc);
        tgt[i] = pb; mem[i] = pb;
    }
}

// ---------------- MFMA GEMM core (m97 structure, 128x128 tile, BK=32) ----------------
// kept for small GEMMs (inp proj w/ PE fusion, proj1) and the fallback path
template<int ACT, int RES>
__device__ __forceinline__ void gemm_body(const u16* __restrict__ A, const u16* __restrict__ W,
                                          const u16* __restrict__ bias, u16* __restrict__ C,
                                          const float* __restrict__ pe, const u16* __restrict__ res,
                                          int K, int ldc){
    __shared__ __align__(16) short As[4096];   // 128 x 32
    __shared__ __align__(16) short Bs[4096];
    const int m0 = blockIdx.x * 128;
    const int n0 = blockIdx.y * 128;
    const int t  = threadIdx.x;
    const int w = t >> 6, lane = t & 63;
    const int quad = lane >> 4, l16 = lane & 15;
    const int wm = (w >> 1) * 64, wn = (w & 1) * 64;

    f32x4 acc[4][4] = {};

    const u16* Ag = A + (size_t)(m0 + (t>>2))*K + (t&3)*8;
    const u16* Wg = W + (size_t)(n0 + (t>>2))*K + (t&3)*8;
    short* Asd = &As[t*8];
    short* Bsd = &Bs[t*8];
    for (int k0 = 0; k0 < K; k0 += 32){
        __syncthreads();
        gload_lds16(Ag + k0,                 Asd);
        gload_lds16(Ag + (size_t)64*K + k0,  Asd + 2048);
        gload_lds16(Wg + k0,                 Bsd);
        gload_lds16(Wg + (size_t)64*K + k0,  Bsd + 2048);
        __syncthreads();
        bf16x8 af[4], bfr[4];
#pragma unroll
        for (int i=0;i<4;i++) af[i]  = *(const bf16x8*)&As[(wm + i*16 + l16)*32 + quad*8];
#pragma unroll
        for (int j=0;j<4;j++) bfr[j] = *(const bf16x8*)&Bs[(wn + j*16 + l16)*32 + quad*8];
#pragma unroll
        for (int i=0;i<4;i++)
#pragma unroll
            for (int j=0;j<4;j++)
                acc[i][j] = __builtin_amdgcn_mfma_f32_16x16x32_bf16(af[i], bfr[j], acc[i][j], 0,0,0);
    }
    // epilogue: C/D layout col=lane&15, row=quad*4+reg
#pragma unroll
    for (int i=0;i<4;i++){
        const int rowb = m0 + wm + i*16 + quad*4;
#pragma unroll
        for (int j=0;j<4;j++){
            const int col = n0 + wn + j*16 + l16;
            const float bv = b2f(bias[col]);
#pragma unroll
            for (int r=0;r<4;r++){
                float v = acc[i][j][r] + bv;
                if (pe) v += pe[((rowb + r) & (SS-1))*HIDD + col];
                if (RES) v += b2f(res[(size_t)(rowb + r)*ldc + col]);
                if (ACT == 1) v = fmaxf(v, 0.0f);
                C[(size_t)(rowb + r)*ldc + col] = f2b(v);
            }
        }
    }
}

template<int ACT, int RES>
__global__ __launch_bounds__(256) void gemm_bt(const u16* __restrict__ A, const u16* __restrict__ W,
                                               const u16* __restrict__ bias, u16* __restrict__ C,
                                               const float* __restrict__ pe, const u16* __restrict__ res,
                                               int K, int ldc){
    gemm_body<ACT,RES>(A, W, bias, C, pe, res, K, ldc);
}

// CA q (from A1=h, cols<1024) + kv (from A2=mem, cols>=1024) in one dispatch (fallback path)
__global__ __launch_bounds__(256) void gemm_dual(const u16* __restrict__ A1, const u16* __restrict__ A2,
                                                 const u16* __restrict__ W, const u16* __restrict__ bias,
                                                 u16* __restrict__ C, int K, int ldc){
    const u16* A = (blockIdx.y < 8) ? A1 : A2;
    gemm_body<0,0>(A, W, bias, C, nullptr, nullptr, K, ldc);
}

// ---------------- 128x256 pipelined GEMM (round-3 proven 3-slot ring, 1 barrier/slice) ----
// kept for ff1 (N=2048 -> grid 512 = 2 blocks/CU).
template<int ACT, int RES, int DUAL, int VT>
__global__ __launch_bounds__(512, 2) void gemm_p(const u16* __restrict__ A1, const u16* __restrict__ A2,
                                                 const u16* __restrict__ W, const u16* __restrict__ bias,
                                                 u16* __restrict__ C, const u16* __restrict__ res,
                                                 u16* __restrict__ vtp, int K, int ldc){
    __shared__ __align__(16) short lds[36864];   // 3 * (4096 A + 8192 B) shorts = 72 KiB
    const int t = threadIdx.x;
    const int w = t >> 6, lane = t & 63;
    const int quad = lane >> 4, l16 = lane & 15;
    const int wm = w >> 2, wn = w & 3;           // 2 x 4 waves
    const int m0 = blockIdx.x * 128;
    const int n0 = blockIdx.y * 256;
    const u16* A = (DUAL && blockIdx.y >= 4) ? A2 : A1;

    const int srow = t >> 2;                     // 0..127
    const int gl   = (t & 3) ^ ((t >> 3) & 3);
    const u16* Ag = A + (size_t)(m0 + srow)*K + gl*8;
    const u16* Bg = W + (size_t)(n0 + srow)*K + gl*8;
    const size_t rstep = (size_t)128 * K;        // B rows 128..255 (row+128 -> same XOR)
    short* ldst = &lds[t*8];

    const int koff = (quad ^ ((l16 >> 1) & 3)) * 8;
    const int aoff = (wm*64 + l16)*32 + koff;
    const int boff = 4096 + (wn*64 + l16)*32 + koff;

    f32x4 acc[4][4] = {};
    const int NS = K >> 5;

    // prologue: slice 0 -> slot0, slice 1 -> slot1
    gload_lds16(Ag,              ldst);
    gload_lds16(Bg,              ldst + 4096);
    gload_lds16(Bg + rstep,      ldst + 8192);
    gload_lds16(Ag + 32,         ldst + 12288);
    gload_lds16(Bg + 32,         ldst + 12288 + 4096);
    gload_lds16(Bg + rstep + 32, ldst + 12288 + 8192);
    asm volatile("s_waitcnt vmcnt(3)" ::: "memory");       // slice 0 landed
    __builtin_amdgcn_s_barrier();
    asm volatile("" ::: "memory");

    int slot = 0, slot2 = 2;
    for (int s = 0; s < NS; ++s){
        const int sb = slot * 12288;
        const short* Ab = &lds[sb + aoff];
        const short* Bb = &lds[sb + boff];
        bf16x8 av[4], bv[4];
#pragma unroll
        for (int i=0;i<4;i++) av[i] = *(const bf16x8*)(Ab + i*512);
#pragma unroll
        for (int j=0;j<4;j++) bv[j] = *(const bf16x8*)(Bb + j*512);
        const int prefetch = (s + 2 < NS);
        if (prefetch){
            const u16* Ap = Ag + (size_t)(s+2)*32;
            const u16* Bp = Bg + (size_t)(s+2)*32;
            short* ld2 = &lds[slot2*12288 + t*8];
            gload_lds16(Ap,         ld2);
            gload_lds16(Bp,         ld2 + 4096);
            gload_lds16(Bp + rstep, ld2 + 8192);
        }
        __builtin_amdgcn_s_setprio(1);
#pragma unroll
        for (int i=0;i<4;i++)
#pragma unroll
            for (int j=0;j<4;j++)
                acc[i][j] = __builtin_amdgcn_mfma_f32_16x16x32_bf16(av[i], bv[j], acc[i][j], 0,0,0);
        __builtin_amdgcn_s_setprio(0);
        if (prefetch) asm volatile("s_waitcnt vmcnt(3)" ::: "memory");   // s+1 landed
        else          asm volatile("s_waitcnt vmcnt(0)" ::: "memory");   // tail: cover s+1
        __builtin_amdgcn_s_barrier();
        asm volatile("" ::: "memory");

        slot  = (slot  == 2) ? 0 : slot  + 1;
        slot2 = (slot2 == 2) ? 0 : slot2 + 1;
    }

    // epilogue: C/D layout col=lane&15, row=quad*4+reg
    if (VT && n0 >= 2048){
#pragma unroll
        for (int i=0;i<4;i++){
            const int rowb = m0 + wm*64 + i*16 + quad*4;
            const int bq = rowb >> 9, sv = rowb & 511;
#pragma unroll
            for (int j=0;j<4;j++){
                const int col = n0 + wn*64 + j*16 + l16;
                const float bvv = b2f(bias[col]);
                const int hh = (col - 2048) >> 8;
                const int dd = (col - 2048) & 255;
                ushort4 ov;
                ov.x = f2b(acc[i][j][0] + bvv);
                ov.y = f2b(acc[i][j][1] + bvv);
                ov.z = f2b(acc[i][j][2] + bvv);
                ov.w = f2b(acc[i][j][3] + bvv);
                *(ushort4*)&vtp[(size_t)((bq*4 + hh)*HDD + dd)*SS + sv] = ov;
            }
        }
    } else {
#pragma unroll
        for (int i=0;i<4;i++){
            const int rowb = m0 + wm*64 + i*16 + quad*4;
#pragma unroll
            for (int j=0;j<4;j++){
                const int col = n0 + wn*64 + j*16 + l16;
                const float bvv = b2f(bias[col]);
#pragma unroll
                for (int r=0;r<4;r++){
                    float v = acc[i][j][r] + bvv;
                    if (RES) v += b2f(res[(size_t)(rowb + r)*ldc + col]);
                    if (ACT == 1) v = fmaxf(v, 0.0f);
                    C[(size_t)(rowb + r)*ldc + col] = f2b(v);
                }
            }
        }
    }
}

// ---------------- 128x128 pipelined GEMM (4 waves, 3-slot ring, 3 blocks/CU) ----------------
// Same invariants as gemm_p (3-slot ring, vmcnt(4)-before-every-barrier, both-sides XOR
// swizzle), scaled to BN=128 with 4 waves (2x2 of 64x64): LDS/slot = A[128][32]+B[128][32]
// = 16 KiB, 3 slots = 48 KiB -> 3 blocks/CU co-resident. Restores cross-block overlap for
// N=1024 GEMMs (grid 512 = 2/CU vs 256 = 1/CU) and gives qkv exactly 2 rounds at 3/CU.
// Per-thread staging: 4 gload_lds16 (A rows t>>2 and t>>2+64, B same; row+64 keeps the
// same XOR phase since 64 % 8 == 0, so one base + 64*K offset).
// Accumulation order per output element identical to gemm_p -> bit-identical results.
template<int ACT, int RES, int DUAL, int VT>
__global__ __launch_bounds__(256, 3) void gemm_p128(const u16* __restrict__ A1, const u16* __restrict__ A2,
                                                    const u16* __restrict__ W, const u16* __restrict__ bias,
                                                    u16* __restrict__ C, const u16* __restrict__ res,
                                                    u16* __restrict__ vtp, int K, int ldc){
    __shared__ __align__(16) short lds[24576];   // 3 * (4096 A + 4096 B) shorts = 48 KiB
    const int t = threadIdx.x;
    const int w = t >> 6, lane = t & 63;
    const int quad = lane >> 4, l16 = lane & 15;
    const int wm = w >> 1, wn = w & 1;           // 2 x 2 waves
    const int m0 = blockIdx.x * 128;
    const int n0 = blockIdx.y * 128;
    const u16* A = (DUAL && blockIdx.y >= 8) ? A2 : A1;

    const int gl = (t & 3) ^ ((t >> 3) & 3);     // pre-swizzled k-granule
    const u16* Ag = A + (size_t)(m0 + (t>>2))*K + gl*8;
    const u16* Bg = W + (size_t)(n0 + (t>>2))*K + gl*8;
    const size_t rstep = (size_t)64 * K;         // rows 64..127 (row+64 -> same XOR)
    short* ldst = &lds[t*8];

    const int koff = (quad ^ ((l16 >> 1) & 3)) * 8;
    const int aoff = (wm*64 + l16)*32 + koff;
    const int boff = 4096 + (wn*64 + l16)*32 + koff;

    f32x4 acc[4][4] = {};
    const int NS = K >> 5;

    auto STG = [&](int ss, int sb){              // 4 loads: A rows [0..64),[64..128), B same
        const size_t ko = (size_t)ss*32;
        gload_lds16(Ag + ko,          ldst + sb);
        gload_lds16(Ag + rstep + ko,  ldst + sb + 2048);
        gload_lds16(Bg + ko,          ldst + sb + 4096);
        gload_lds16(Bg + rstep + ko,  ldst + sb + 6144);
    };

    // prologue: slice 0 -> slot0, slice 1 -> slot1
    STG(0, 0); STG(1, 8192);
    asm volatile("s_waitcnt vmcnt(4)" ::: "memory");       // slice 0 landed
    __builtin_amdgcn_s_barrier();
    asm volatile("" ::: "memory");

    int slot = 0, slot2 = 2;
    for (int s = 0; s < NS; ++s){
        const int sb = slot * 8192;
        const short* Ab = &lds[sb + aoff];
        const short* Bb = &lds[sb + boff];
        bf16x8 av[4], bv[4];
#pragma unroll
        for (int i=0;i<4;i++) av[i] = *(const bf16x8*)(Ab + i*512);
#pragma unroll
        for (int j=0;j<4;j++) bv[j] = *(const bf16x8*)(Bb + j*512);
        const int prefetch = (s + 2 < NS);
        if (prefetch) STG(s+2, slot2*8192);
        __builtin_amdgcn_s_setprio(1);
#pragma unroll
        for (int i=0;i<4;i++)
#pragma unroll
            for (int j=0;j<4;j++)
                acc[i][j] = __builtin_amdgcn_mfma_f32_16x16x32_bf16(av[i], bv[j], acc[i][j], 0,0,0);
        __builtin_amdgcn_s_setprio(0);
        if (prefetch) asm volatile("s_waitcnt vmcnt(4)" ::: "memory");   // s+1 landed
        else          asm volatile("s_waitcnt vmcnt(0)" ::: "memory");   // tail: cover s+1
        __builtin_amdgcn_s_barrier();
        asm volatile("" ::: "memory");

        slot  = (slot  == 2) ? 0 : slot  + 1;
        slot2 = (slot2 == 2) ? 0 : slot2 + 1;
    }

    // epilogue: C/D layout col=lane&15, row=quad*4+reg
    if (VT && n0 >= 2048){
#pragma unroll
        for (int i=0;i<4;i++){
            const int rowb = m0 + wm*64 + i*16 + quad*4;
            const int bq = rowb >> 9, sv = rowb & 511;
#pragma unroll
            for (int j=0;j<4;j++){
                const int col = n0 + wn*64 + j*16 + l16;
                const float bvv = b2f(bias[col]);
                const int hh = (col - 2048) >> 8;
                const int dd = (col - 2048) & 255;
                ushort4 ov;
                ov.x = f2b(acc[i][j][0] + bvv);
                ov.y = f2b(acc[i][j][1] + bvv);
                ov.z = f2b(acc[i][j][2] + bvv);
                ov.w = f2b(acc[i][j][3] + bvv);
                *(ushort4*)&vtp[(size_t)((bq*4 + hh)*HDD + dd)*SS + sv] = ov;
            }
        }
    } else {
#pragma unroll
        for (int i=0;i<4;i++){
            const int rowb = m0 + wm*64 + i*16 + quad*4;
#pragma unroll
            for (int j=0;j<4;j++){
                const int col = n0 + wn*64 + j*16 + l16;
                const float bvv = b2f(bias[col]);
#pragma unroll
                for (int r=0;r<4;r++){
                    float v = acc[i][j][r] + bvv;
                    if (RES) v += b2f(res[(size_t)(rowb + r)*ldc + col]);
                    if (ACT == 1) v = fmaxf(v, 0.0f);
                    C[(size_t)(rowb + r)*ldc + col] = f2b(v);
                }
            }
        }
    }
}

// ---------------- V transpose (fallback path only) ----------------
__global__ __launch_bounds__(256) void vt_kernel(const u16* __restrict__ qkv, u16* __restrict__ vt){
    __shared__ __align__(16) u16 tile[64][72];
    const int bh = blockIdx.x, b = bh >> 2, h = bh & 3;
    const int s0 = blockIdx.y*64, d0 = blockIdx.z*64;
    const int t = threadIdx.x;
#pragma unroll
    for (int it=0; it<2; it++){
        const int u = it*256 + t;
        const int sl = u >> 3, dc = (u & 7)*8;
        *(uint4*)&tile[sl][dc] =
            *(const uint4*)(qkv + (size_t)(b*SS + s0 + sl)*3072 + 2*DD + h*HDD + d0 + dc);
    }
    __syncthreads();
#pragma unroll
    for (int it=0; it<2; it++){
        const int u = it*256 + t;
        const int dl = u >> 3, sc = (u & 7)*8;
        uint4 tv; u16* tmp = (u16*)&tv;
#pragma unroll
        for (int j=0;j<8;j++) tmp[j] = tile[sc+j][dl];
        *(uint4*)(vt + (size_t)(bh*HDD + d0 + dl)*SS + s0 + sc) = tv;
    }
}

// ---------------- flash attention (2-slot K/V ring, counted vmcnt, XCD-local grid) ----
__global__ __launch_bounds__(256) void flash_attn(const u16* __restrict__ qkv, const u16* __restrict__ vt,
                                                  u16* __restrict__ ao, const int causal){
    __shared__ __align__(16) short Kt[2][8192];
    __shared__ __align__(16) short Vs[2][8192];
    __shared__ __align__(16) short pbuf[4][16][40];
    const int bh = blockIdx.x;
    // heavy causal q-tiles first (load-balance the tail)
    const int qt = causal ? (gridDim.y - 1 - blockIdx.y) : blockIdx.y;
    const int b = bh >> 2, h = bh & 3;
    const int t = threadIdx.x, w = t >> 6, lane = t & 63;
    const int quad = lane >> 4, l16 = lane & 15;
    const int qbase = qt * 64;

    const u16* qp = qkv + (size_t)(b*SS + qbase + w*16 + l16)*3072 + h*HDD + quad*8;
    bf16x8 qf[8];
#pragma unroll
    for (int kc=0;kc<8;kc++) qf[kc] = *(const bf16x8*)(qp + kc*32);

    f32x4 o[16] = {};
    float mrow[4] = {-1e30f,-1e30f,-1e30f,-1e30f};
    float lrow[4] = {0.f,0.f,0.f,0.f};

    const int ntiles = causal ? (qbase/32 + 2) : (SS/32);
    const int myq = qbase + w*16 + quad*4;

    const u16* Kg = qkv + (size_t)(b*SS)*3072 + DD + h*HDD;
    const u16* Vg = vt + (size_t)bh*HDD*SS;
    const int keyl8 = t >> 5;
    const int kslot = t & 31;
    const int vrow4 = t >> 2;
    const int vslot = t & 3;

    // stage K/V tile kt2 into ring slot sl (same swizzled layout as before)
    auto stage = [&](int kt2, int sl){
        const int kv0s = kt2*32;
#pragma unroll
        for (int j=0;j<4;j++){
            const int keyl = j*8 + keyl8;
            const int ck   = kslot ^ keyl;
            gload_lds16(Kg + (size_t)(kv0s + keyl)*3072 + ck*8, &Kt[sl][j*2048 + t*8]);
            const int d  = j*64 + vrow4;
            const int cv = vslot ^ (d&3) ^ ((d>>2)&3);
            gload_lds16(Vg + (size_t)d*SS + kv0s + cv*8, &Vs[sl][j*2048 + t*8]);
        }
    };

    stage(0, 0);
    for (int kt=0; kt<ntiles; kt++){
        const int kv0 = kt*32;
        const int sl = kt & 1;
        if (kt + 1 < ntiles){
            stage(kt+1, sl^1);
            asm volatile("s_waitcnt vmcnt(8)" ::: "memory");   // tile kt landed; kt+1 in flight
        } else {
            asm volatile("s_waitcnt vmcnt(0)" ::: "memory");   // tail drain
        }
        __builtin_amdgcn_s_barrier();                          // tile kt visible to all
        asm volatile("" ::: "memory");

        f32x4 sc0 = {0.f,0.f,0.f,0.f}, sc1 = {0.f,0.f,0.f,0.f};
#pragma unroll
        for (int kk=0;kk<8;kk++){
            const int ch = kk*4 + quad;
            sc0 = __builtin_amdgcn_mfma_f32_16x16x32_bf16(qf[kk],
                    *(const bf16x8*)&Kt[sl][l16*256 + (ch ^ l16)*8], sc0, 0,0,0);
            sc1 = __builtin_amdgcn_mfma_f32_16x16x32_bf16(qf[kk],
                    *(const bf16x8*)&Kt[sl][(16+l16)*256 + (ch ^ (16+l16))*8], sc1, 0,0,0);
        }
#pragma unroll
        for (int r=0;r<4;r++){
            float a0 = sc0[r]*0.0625f, a1 = sc1[r]*0.0625f;
            if (causal){
                if (kv0 + l16 > myq + r)      a0 = -1e9f;
                if (kv0 + 16 + l16 > myq + r) a1 = -1e9f;
            }
            float tm = fmaxf(a0,a1);
            tm = fmaxf(tm, __shfl_xor(tm,1)); tm = fmaxf(tm, __shfl_xor(tm,2));
            tm = fmaxf(tm, __shfl_xor(tm,4)); tm = fmaxf(tm, __shfl_xor(tm,8));
            const float mnew  = fmaxf(mrow[r], tm);
            const float alpha = __expf(mrow[r] - mnew);
            const float p0 = __expf(a0 - mnew), p1 = __expf(a1 - mnew);
            float rs = p0 + p1;
            rs += __shfl_xor(rs,1); rs += __shfl_xor(rs,2);
            rs += __shfl_xor(rs,4); rs += __shfl_xor(rs,8);
            lrow[r] = lrow[r]*alpha + rs;
            mrow[r] = mnew;
#pragma unroll
            for (int dt=0;dt<16;dt++) o[dt][r] *= alpha;
            pbuf[w][quad*4+r][l16]      = (short)f2b(p0);
            pbuf[w][quad*4+r][16 + l16] = (short)f2b(p1);
        }
        asm volatile("s_waitcnt lgkmcnt(0)" ::: "memory");     // own-wave pbuf writes retired

        const bf16x8 pf = *(const bf16x8*)&pbuf[w][l16][quad*8];
#pragma unroll
        for (int dt=0;dt<16;dt++){
            const int d = dt*16 + l16;
            o[dt] = __builtin_amdgcn_mfma_f32_16x16x32_bf16(pf,
                      *(const bf16x8*)&Vs[sl][d*32 + ((quad ^ (d&3) ^ ((d>>2)&3)))*8], o[dt], 0,0,0);
        }
        asm volatile("s_waitcnt lgkmcnt(0)" ::: "memory");     // slot reads retired
        __builtin_amdgcn_s_barrier();                          // safe to overwrite slot sl^1
        asm volatile("" ::: "memory");
    }
#pragma unroll
    for (int r=0;r<4;r++){
        const size_t row = (size_t)(b*SS + myq + r);
        const float inv = 1.0f / lrow[r];
#pragma unroll
        for (int dt=0;dt<16;dt++)
            ao[row*DD + h*HDD + dt*16 + l16] = f2b(o[dt][r]*inv);
    }
}

// ---------------- LayerNorm over pre-summed y, writes h ----------------
__global__ __launch_bounds__(256) void ln_kernel(u16* __restrict__ h, const u16* __restrict__ y,
                                                 const void* __restrict__ lnw, const void* __restrict__ lnb,
                                                 size_t off, const int* __restrict__ flag){
    const int f = flag[0];
    const int m = blockIdx.x, t = threadIdx.x;
    __shared__ float red[8];
    const ushort4 yv = *(const ushort4*)&y[(size_t)m*DD + t*4];
    float vv[4]; float sum = 0.f;
    vv[0] = b2f(yv.x); vv[1] = b2f(yv.y); vv[2] = b2f(yv.z); vv[3] = b2f(yv.w);
#pragma unroll
    for (int j=0;j<4;j++) sum += vv[j];
    for (int o2=1; o2<64; o2<<=1) sum += __shfl_xor(sum, o2);
    if ((t&63)==0) red[t>>6] = sum;
    __syncthreads();
    const float mean = (red[0]+red[1]+red[2]+red[3]) * (1.f/DD);
    float vs = 0.f;
#pragma unroll
    for (int j=0;j<4;j++){ const float d = vv[j]-mean; vs += d*d; }
    for (int o2=1; o2<64; o2<<=1) vs += __shfl_xor(vs, o2);
    if ((t&63)==0) red[4 + (t>>6)] = vs;
    __syncthreads();
    const float var = (red[4]+red[5]+red[6]+red[7]) * (1.f/DD);
    const float rstd = rsqrtf(var + 1e-5f);
    ushort4 ov;
    ov.x = f2b((vv[0]-mean)*rstd*ldin(lnw, off+t*4+0, f) + ldin(lnb, off+t*4+0, f));
    ov.y = f2b((vv[1]-mean)*rstd*ldin(lnw, off+t*4+1, f) + ldin(lnb, off+t*4+1, f));
    ov.z = f2b((vv[2]-mean)*rstd*ldin(lnw, off+t*4+2, f) + ldin(lnb, off+t*4+2, f));
    ov.w = f2b((vv[3]-mean)*rstd*ldin(lnw, off+t*4+3, f) + ldin(lnb, off+t*4+3, f));
    *(ushort4*)&h[(size_t)m*DD + t*4] = ov;
}

// ---------------- output head ----------------
__global__ __launch_bounds__(256) void final_kernel(const u16* __restrict__ p1, const void* __restrict__ w2,
                                                    const void* __restrict__ b2p, const int* __restrict__ basis,
                                                    void* __restrict__ out, const int* __restrict__ flag){
    const int f = flag[0];
    const int blk = blockIdx.x;            // B*L
    const int b = blk / LL, l = blk % LL;
    const int t = threadIdx.x;
    __shared__ float red[4];
    const ushort2 pv = *(const ushort2*)&p1[(size_t)(b*SS + l + 1)*HIDD + t*2];
    float acc;
    {
        float v0 = b2f(pv.x); v0 = v0 >= 0.f ? v0 : 0.01f*v0;
        float v1 = b2f(pv.y); v1 = v1 >= 0.f ? v1 : 0.01f*v1;
        acc = v0 * ldin(w2, t*2+0, f) + v1 * ldin(w2, t*2+1, f);
    }
    for (int off=1; off<64; off<<=1) acc += __shfl_xor(acc, off);
    if ((t & 63) == 0) red[t>>6] = acc;
    __syncthreads();
    if (t == 0){
        const float r = red[0]+red[1]+red[2]+red[3] + ldin(b2p, 0, f);
        const float v = (l < basis[b]) ? r : 0.0f;
        if (f) ((float*)out)[blk] = v;
        else   ((u16*)out)[blk] = f2b(v);
    }
}

extern "C" void kernel_launch(void* const* d_in, const int* in_sizes, int n_in,
                              void* d_out, int out_size, void* d_ws, size_t ws_size,
                              hipStream_t stream){
    const void* gs       = d_in[0];
    const void* prev     = d_in[1];
    const void* cur      = d_in[2];
    const void* target   = d_in[3];
    const void* bos      = d_in[4];
    const void* inp_w1   = d_in[5];
    const void* inp_b1   = d_in[6];
    const void* inp_w2   = d_in[7];
    const void* inp_b2   = d_in[8];
    const void* sa_qkv_w = d_in[9];
    const void* sa_qkv_b = d_in[10];
    const void* sa_out_w = d_in[11];
    const void* sa_out_b = d_in[12];
    const void* ca_qkv_w = d_in[13];
    const void* ca_qkv_b = d_in[14];
    const void* ca_out_w = d_in[15];
    const void* ca_out_b = d_in[16];
    const void* ln_w     = d_in[17];
    const void* ln_b     = d_in[18];
    const void* ff_w1    = d_in[19];
    const void* ff_b1    = d_in[20];
    const void* ff_w2    = d_in[21];
    const void* ff_b2    = d_in[22];
    const void* proj_w1  = d_in[23];
    const void* proj_b1  = d_in[24];
    const void* proj_w2  = d_in[25];
    const void* proj_b2  = d_in[26];
    const int*  basis    = (const int*)d_in[27];

    size_t off = 0;
    auto carve = [&](size_t bytes)->void*{
        void* p = (char*)d_ws + off;
        off += (bytes + 255) & ~(size_t)255;
        return p;
    };
    // common activation buffers (~118.6 MB)
    int*   flag = (int*)  carve(256);
    u16*   qkv  = (u16*)  carve((size_t)MTOK*3*DD*2);   // also U / ff1
    u16*   h    = (u16*)  carve((size_t)MTOK*DD*2);
    u16*   mem  = (u16*)  carve((size_t)MTOK*DD*2);
    u16*   ao   = (u16*)  carve((size_t)MTOK*DD*2);
    u16*   vty  = (u16*)  carve((size_t)MTOK*DD*2);     // vt / y / p1
    float* pe   = (float*)carve((size_t)SS*HIDD*4);
    u16* U  = qkv;
    u16* vt = vty;
    u16* y  = vty;

    // full-preconvert weight region (~77.1 MB)
    const size_t NW_TOTAL = 38535168, NB_TOTAL = 34816;
    const bool full = (ws_size >= off + ((NW_TOTAL*2+255)&~(size_t)255) + ((NB_TOTAL*2+255)&~(size_t)255));

    detect_kernel<<<dim3(1), 64, 0, stream>>>((const u16*)ln_w, flag);
    pe_kernel    <<<dim3(SS*HIDD/256),  256, 0, stream>>>(pe);
    inp_u_kernel <<<dim3(MTOK*HIDD/256),256, 0, stream>>>(bos, target, inp_w1, inp_b1, U, flag);

    if (full){
        u16* wbuf = (u16*)carve(NW_TOTAL*2);
        u16* bbuf = (u16*)carve(NB_TOTAL*2);
        // weight-region element offsets
        u16* w_saqkv = wbuf + 0;          // 3 x 3145728
        u16* w_saout = wbuf + 9437184;    // 3 x 1048576
        u16* w_caqkv = wbuf + 12582912;   // 3 x 3145728
        u16* w_caout = wbuf + 22020096;   // 3 x 1048576
        u16* w_ff1   = wbuf + 25165824;   // 3 x 2097152
        u16* w_ff2   = wbuf + 31457280;   // 3 x 2097152
        u16* w_inp2  = wbuf + 37748736;   // 262144
        u16* w_proj1 = wbuf + 38010880;   // 524288
        u16* b_saqkv = bbuf + 0;          // 3 x 3072
        u16* b_saout = bbuf + 9216;       // 3 x 1024
        u16* b_caqkv = bbuf + 12288;      // 3 x 3072
        u16* b_caout = bbuf + 21504;      // 3 x 1024
        u16* b_ff1   = bbuf + 24576;      // 3 x 2048
        u16* b_ff2   = bbuf + 30720;      // 3 x 1024
        u16* b_inp2  = bbuf + 33792;      // 512
        u16* b_proj1 = bbuf + 34304;      // 512

        // all weight conversions in ONE dispatch (8 jobs, blockIdx.y = job)
        WJobs jobs;
        jobs.j[0] = { inp_w2,   inp_b2,   w_inp2,  b_inp2,  HIDD*HIDD, HIDD   };
        jobs.j[1] = { sa_qkv_w, sa_qkv_b, w_saqkv, b_saqkv, 3*3*DD*DD, 3*3*DD };
        jobs.j[2] = { sa_out_w, sa_out_b, w_saout, b_saout, 3*DD*DD,   3*DD   };
        jobs.j[3] = { ca_qkv_w, ca_qkv_b, w_caqkv, b_caqkv, 3*3*DD*DD, 3*3*DD };
        jobs.j[4] = { ca_out_w, ca_out_b, w_caout, b_caout, 3*DD*DD,   3*DD   };
        jobs.j[5] = { ff_w1,    ff_b1,    w_ff1,   b_ff1,   3*DFFF*DD, 3*DFFF };
        jobs.j[6] = { ff_w2,    ff_b2,    w_ff2,   b_ff2,   3*DD*DFFF, 3*DD   };
        jobs.j[7] = { proj_w1,  proj_b1,  w_proj1, b_proj1, HIDD*DD,   HIDD   };
        wconv8_kernel<<<dim3(512,8),256,0,stream>>>(jobs, flag);

        gemm_bt<0,0> <<<dim3(64,4),  256, 0, stream>>>(U, w_inp2, b_inp2, h, pe, nullptr, HIDD, DD);
        concat_kernel<<<dim3(MTOK*DD/256), 256, 0, stream>>>(gs, prev, cur, h, mem, flag);

        for (int l = 0; l < 3; l++){
            gemm_p128<0,0,0,1><<<dim3(64,24),256,0,stream>>>(h, nullptr, w_saqkv + (size_t)l*3*DD*DD,
                                                             b_saqkv + l*3*DD, qkv, nullptr, vt, DD, 3*DD);
            flash_attn        <<<dim3(64,8),  256,0,stream>>>(qkv, vt, ao, 1);
            gemm_p128<0,1,0,0><<<dim3(64,8),  256,0,stream>>>(ao, nullptr, w_saout + (size_t)l*DD*DD,
                                                              b_saout + l*DD, y, h, nullptr, DD, DD);
            ln_kernel         <<<dim3(MTOK),  256,0,stream>>>(h, y, ln_w, ln_b, (size_t)(l*3+0)*DD, flag);

            gemm_p128<0,0,1,1><<<dim3(64,24),256,0,stream>>>(h, mem, w_caqkv + (size_t)l*3*DD*DD,
                                                             b_caqkv + l*3*DD, qkv, nullptr, vt, DD, 3*DD);
            flash_attn        <<<dim3(64,8),  256,0,stream>>>(qkv, vt, ao, 0);
            gemm_p128<0,1,0,0><<<dim3(64,8),  256,0,stream>>>(ao, nullptr, w_caout + (size_t)l*DD*DD,
                                                              b_caout + l*DD, y, h, nullptr, DD, DD);
            ln_kernel         <<<dim3(MTOK),  256,0,stream>>>(h, y, ln_w, ln_b, (size_t)(l*3+1)*DD, flag);

            gemm_p<1,0,0,0>   <<<dim3(64,8), 512,0,stream>>>(h, nullptr, w_ff1 + (size_t)l*DFFF*DD,
                                                             b_ff1 + l*DFFF, qkv, nullptr, nullptr, DD, DFFF);
            gemm_p128<0,1,0,0><<<dim3(64,8), 256,0,stream>>>(qkv, nullptr, w_ff2 + (size_t)l*DD*DFFF,
                                                             b_ff2 + l*DD, y, h, nullptr, DFFF, DD);
            ln_kernel         <<<dim3(MTOK), 256,0,stream>>>(h, y, ln_w, ln_b, (size_t)(l*3+2)*DD, flag);
        }
        gemm_bt<0,0><<<dim3(64,4), 256,0,stream>>>(h, w_proj1, b_proj1, y, nullptr, nullptr, DD, HIDD);
        final_kernel<<<dim3(BB*LL),256,0,stream>>>(y, proj_w2, proj_b2, basis, d_out, flag);
    } else {
        // fallback: round-5 proven two-slot scheme (+ residual fusion & dual CA)
        u16* s0w = (u16*)carve((size_t)3*DD*DD*2);
        u16* s0b = (u16*)carve((size_t)4096*2);
        u16* s1w = (u16*)carve((size_t)3*DD*DD*2);
        u16* s1b = (u16*)carve((size_t)4096*2);
        const dim3 wcg(512);

        wconv_kernel<<<wcg,256,0,stream>>>(inp_w2, 0, inp_b2, 0, s0w, s0b, HIDD*HIDD, HIDD, flag);
        gemm_bt<0,0><<<dim3(64,4), 256,0,stream>>>(U, s0w, s0b, h, pe, nullptr, HIDD, DD);
        concat_kernel<<<dim3(MTOK*DD/256),256,0,stream>>>(gs, prev, cur, h, mem, flag);

        for (int l = 0; l < 3; l++){
            wconv_kernel<<<wcg,256,0,stream>>>(sa_qkv_w, (size_t)l*3*DD*DD, sa_qkv_b, (size_t)l*3*DD,
                                               s1w, s1b, 3*DD*DD, 3*DD, flag);
            gemm_bt<0,0><<<dim3(64,24),256,0,stream>>>(h, s1w, s1b, qkv, nullptr, nullptr, DD, 3*DD);
            vt_kernel   <<<dim3(64,8,4),256,0,stream>>>(qkv, vt);
            flash_attn  <<<dim3(64,8),  256,0,stream>>>(qkv, vt, ao, 1);
            wconv_kernel<<<wcg,256,0,stream>>>(sa_out_w, (size_t)l*DD*DD, sa_out_b, (size_t)l*DD,
                                               s0w, s0b, DD*DD, DD, flag);
            gemm_bt<0,1><<<dim3(64,8), 256,0,stream>>>(ao, s0w, s0b, y, nullptr, h, DD, DD);
            ln_kernel   <<<dim3(MTOK), 256,0,stream>>>(h, y, ln_w, ln_b, (size_t)(l*3+0)*DD, flag);

            wconv_kernel<<<wcg,256,0,stream>>>(ca_qkv_w, (size_t)l*3*DD*DD, ca_qkv_b, (size_t)l*3*DD,
                                               s1w, s1b, 3*DD*DD, 3*DD, flag);
            gemm_dual   <<<dim3(64,24),256,0,stream>>>(h, mem, s1w, s1b, qkv, DD, 3*DD);
            vt_kernel   <<<dim3(64,8,4),256,0,stream>>>(qkv, vt);
            flash_attn  <<<dim3(64,8),  256,0,stream>>>(qkv, vt, ao, 0);
            wconv_kernel<<<wcg,256,0,stream>>>(ca_out_w, (size_t)l*DD*DD, ca_out_b, (size_t)l*DD,
                                               s0w, s0b, DD*DD, DD, flag);
            gemm_bt<0,1><<<dim3(64,8), 256,0,stream>>>(ao, s0w, s0b, y, nullptr, h, DD, DD);
            ln_kernel   <<<dim3(MTOK), 256,0,stream>>>(h, y, ln_w, ln_b, (size_t)(l*3+1)*DD, flag);

            wconv_kernel<<<wcg,256,0,stream>>>(ff_w1, (size_t)l*DFFF*DD, ff_b1, (size_t)l*DFFF,
                                               s1w, s1b, DFFF*DD, DFFF, flag);
            gemm_bt<1,0><<<dim3(64,16),256,0,stream>>>(h, s1w, s1b, qkv, nullptr, nullptr, DD, DFFF);
            wconv_kernel<<<wcg,256,0,stream>>>(ff_w2, (size_t)l*DD*DFFF, ff_b2, (size_t)l*DD,
                                               s0w, s0b, DD*DFFF, DD, flag);
            gemm_bt<0,1><<<dim3(64,8), 256,0,stream>>>(qkv, s0w, s0b, y, nullptr, h, DFFF, DD);
            ln_kernel   <<<dim3(MTOK), 256,0,stream>>>(h, y, ln_w, ln_b, (size_t)(l*3+2)*DD, flag);
        }
        wconv_kernel<<<wcg,256,0,stream>>>(proj_w1, 0, proj_b1, 0, s1w, s1b, HIDD*DD, HIDD, flag);
        gemm_bt<0,0><<<dim3(64,4), 256,0,stream>>>(h, s1w, s1b, y, nullptr, nullptr, DD, HIDD);
        final_kernel<<<dim3(BB*LL),256,0,stream>>>(y, proj_w2, proj_b2, basis, d_out, flag);
    }
}

// Round 8
// 1444.575 us; speedup vs baseline: 1.0265x; 1.0265x over previous
//
#include <hip/hip_runtime.h>

typedef unsigned short u16;
typedef __attribute__((ext_vector_type(8))) short bf16x8;
typedef __attribute__((ext_vector_type(4))) float f32x4;

#define BB   16
#define LL   511
#define SS   512
#define DD   1024
#define HIDD 512
#define DFFF 2048
#define NHH  4
#define HDD  256
#define MTOK (BB*SS)   // 8192

__device__ __forceinline__ float b2f(u16 u){ return __uint_as_float(((unsigned)u)<<16); }
__device__ __forceinline__ u16 f2b(float f){
    unsigned x = __float_as_uint(f);
    return (u16)((x + 0x7fffu + ((x>>16)&1u)) >> 16);   // RNE
}
__device__ __forceinline__ float ldin(const void* p, size_t i, int f){
    return f ? ((const float*)p)[i] : b2f(((const u16*)p)[i]);
}
__device__ __forceinline__ void gload_lds16(const void* g, void* l){
    __builtin_amdgcn_global_load_lds((const __attribute__((address_space(1))) unsigned*)g,
                                     (__attribute__((address_space(3))) unsigned*)l, 16, 0, 0);
}

// ---------------- dtype detect ----------------
__global__ void detect_kernel(const u16* __restrict__ lnw, int* __restrict__ flag){
    if (threadIdx.x == 0 && blockIdx.x == 0) flag[0] = (lnw[0] == 0x3F80) ? 0 : 1;
}

// ---------------- weight (+bias) conversion into bf16 scratch ----------------
__global__ void wconv_kernel(const void* __restrict__ w, size_t woff,
                             const void* __restrict__ b, size_t boff,
                             u16* __restrict__ dw, u16* __restrict__ db,
                             int nw, int nb, const int* __restrict__ flag){
    const int f = flag[0];
    const int idx = blockIdx.x*256 + threadIdx.x;
    const int stride = gridDim.x * 256;
    if (f){
        const float* wf = (const float*)w + woff;
        const float* bf = (const float*)b + boff;
        for (int i = idx*4; i < nw; i += stride*4){
            const float4 v = *(const float4*)&wf[i];
            ushort4 o; o.x=f2b(v.x); o.y=f2b(v.y); o.z=f2b(v.z); o.w=f2b(v.w);
            *(ushort4*)&dw[i] = o;
        }
        for (int i = idx*4; i < nb; i += stride*4){
            const float4 v = *(const float4*)&bf[i];
            ushort4 o; o.x=f2b(v.x); o.y=f2b(v.y); o.z=f2b(v.z); o.w=f2b(v.w);
            *(ushort4*)&db[i] = o;
        }
    } else {
        const u16* wu = (const u16*)w + woff;
        const u16* bu = (const u16*)b + boff;
        for (int i = idx*4; i < nw; i += stride*4) *(ushort4*)&dw[i] = *(const ushort4*)&wu[i];
        for (int i = idx*4; i < nb; i += stride*4) *(ushort4*)&db[i] = *(const ushort4*)&bu[i];
    }
}

// batched variant: 8 conversion jobs in ONE dispatch (blockIdx.y = job)
struct WJob  { const void* w; const void* b; u16* dw; u16* db; int nw; int nb; };
struct WJobs { WJob j[8]; };
__global__ void wconv8_kernel(WJobs jobs, const int* __restrict__ flag){
    const int f = flag[0];
    const WJob J = jobs.j[blockIdx.y];
    const int idx = blockIdx.x*256 + threadIdx.x;
    const int stride = gridDim.x * 256;
    if (f){
        const float* wf = (const float*)J.w;
        const float* bf = (const float*)J.b;
        for (int i = idx*4; i < J.nw; i += stride*4){
            const float4 v = *(const float4*)&wf[i];
            ushort4 o; o.x=f2b(v.x); o.y=f2b(v.y); o.z=f2b(v.z); o.w=f2b(v.w);
            *(ushort4*)&J.dw[i] = o;
        }
        for (int i = idx*4; i < J.nb; i += stride*4){
            const float4 v = *(const float4*)&bf[i];
            ushort4 o; o.x=f2b(v.x); o.y=f2b(v.y); o.z=f2b(v.z); o.w=f2b(v.w);
            *(ushort4*)&J.db[i] = o;
        }
    } else {
        const u16* wu = (const u16*)J.w;
        const u16* bu = (const u16*)J.b;
        for (int i = idx*4; i < J.nw; i += stride*4) *(ushort4*)&J.dw[i] = *(const ushort4*)&wu[i];
        for (int i = idx*4; i < J.nb; i += stride*4) *(ushort4*)&J.db[i] = *(const ushort4*)&bu[i];
    }
}

// ---------------- positional encoding ----------------
__global__ void pe_kernel(float* __restrict__ pe){
    const int i = blockIdx.x*256 + threadIdx.x;       // < 512*512
    const int s = i >> 9, c = i & 511;
    const float div = expf(-(float)(c & ~1) * (logf(10000.0f)/512.0f));
    const float ang = (float)s * div;
    pe[i] = (c & 1) ? cosf(ang) : sinf(ang);
}

// ---------------- input proj stage 1 ----------------
__global__ void inp_u_kernel(const void* __restrict__ bos, const void* __restrict__ target,
                             const void* __restrict__ w1, const void* __restrict__ b1,
                             u16* __restrict__ U, const int* __restrict__ flag){
    const int f = flag[0];
    const int i = blockIdx.x*256 + threadIdx.x;       // < MTOK*HIDD
    const int m = i >> 9, c = i & 511;
    const int b = m >> 9, s = m & 511;
    const float ts = (s == 0) ? ldin(bos, 0, f) : ldin(target, b*LL + s - 1, f);
    float v = ts * ldin(w1, c, f) + ldin(b1, c, f);
    U[i] = f2b(v >= 0.f ? v : 0.01f*v);
}

// ---------------- concat ----------------
__global__ void concat_kernel(const void* __restrict__ gs, const void* __restrict__ prev,
                              const void* __restrict__ cur, u16* __restrict__ tgt,
                              u16* __restrict__ mem, const int* __restrict__ flag){
    const int f = flag[0];
    const int i = blockIdx.x*256 + threadIdx.x;       // < MTOK*DD
    const int m = i >> 10, c = i & 1023;
    if (c < 512){
        mem[i] = f2b(ldin(gs, (size_t)m*512 + c, f));
    } else {
        const float pc = (c < 768) ? ldin(prev, (m>>9)*256 + (c-512), f)
                                   : ldin(cur,  (m>>9)*256 + (c-768), f);
        const u16 pb = f2b(pc);
        tgt[i] = pb; mem[i] = pb;
    }
}

// ---------------- MFMA GEMM core (m97 structure, 128x128 tile, BK=32) ----------------
// kept for small GEMMs (inp proj w/ PE fusion, proj1) and the fallback path
template<int ACT, int RES>
__device__ __forceinline__ void gemm_body(const u16* __restrict__ A, const u16* __restrict__ W,
                                          const u16* __restrict__ bias, u16* __restrict__ C,
                                          const float* __restrict__ pe, const u16* __restrict__ res,
                                          int K, int ldc){
    __shared__ __align__(16) short As[4096];   // 128 x 32
    __shared__ __align__(16) short Bs[4096];
    const int m0 = blockIdx.x * 128;
    const int n0 = blockIdx.y * 128;
    const int t  = threadIdx.x;
    const int w = t >> 6, lane = t & 63;
    const int quad = lane >> 4, l16 = lane & 15;
    const int wm = (w >> 1) * 64, wn = (w & 1) * 64;

    f32x4 acc[4][4] = {};

    const u16* Ag = A + (size_t)(m0 + (t>>2))*K + (t&3)*8;
    const u16* Wg = W + (size_t)(n0 + (t>>2))*K + (t&3)*8;
    short* Asd = &As[t*8];
    short* Bsd = &Bs[t*8];
    for (int k0 = 0; k0 < K; k0 += 32){
        __syncthreads();
        gload_lds16(Ag + k0,                 Asd);
        gload_lds16(Ag + (size_t)64*K + k0,  Asd + 2048);
        gload_lds16(Wg + k0,                 Bsd);
        gload_lds16(Wg + (size_t)64*K + k0,  Bsd + 2048);
        __syncthreads();
        bf16x8 af[4], bfr[4];
#pragma unroll
        for (int i=0;i<4;i++) af[i]  = *(const bf16x8*)&As[(wm + i*16 + l16)*32 + quad*8];
#pragma unroll
        for (int j=0;j<4;j++) bfr[j] = *(const bf16x8*)&Bs[(wn + j*16 + l16)*32 + quad*8];
#pragma unroll
        for (int i=0;i<4;i++)
#pragma unroll
            for (int j=0;j<4;j++)
                acc[i][j] = __builtin_amdgcn_mfma_f32_16x16x32_bf16(af[i], bfr[j], acc[i][j], 0,0,0);
    }
    // epilogue: C/D layout col=lane&15, row=quad*4+reg
#pragma unroll
    for (int i=0;i<4;i++){
        const int rowb = m0 + wm + i*16 + quad*4;
#pragma unroll
        for (int j=0;j<4;j++){
            const int col = n0 + wn + j*16 + l16;
            const float bv = b2f(bias[col]);
#pragma unroll
            for (int r=0;r<4;r++){
                float v = acc[i][j][r] + bv;
                if (pe) v += pe[((rowb + r) & (SS-1))*HIDD + col];
                if (RES) v += b2f(res[(size_t)(rowb + r)*ldc + col]);
                if (ACT == 1) v = fmaxf(v, 0.0f);
                C[(size_t)(rowb + r)*ldc + col] = f2b(v);
            }
        }
    }
}

template<int ACT, int RES>
__global__ __launch_bounds__(256) void gemm_bt(const u16* __restrict__ A, const u16* __restrict__ W,
                                               const u16* __restrict__ bias, u16* __restrict__ C,
                                               const float* __restrict__ pe, const u16* __restrict__ res,
                                               int K, int ldc){
    gemm_body<ACT,RES>(A, W, bias, C, pe, res, K, ldc);
}

// CA q (from A1=h, cols<1024) + kv (from A2=mem, cols>=1024) in one dispatch (fallback path)
__global__ __launch_bounds__(256) void gemm_dual(const u16* __restrict__ A1, const u16* __restrict__ A2,
                                                 const u16* __restrict__ W, const u16* __restrict__ bias,
                                                 u16* __restrict__ C, int K, int ldc){
    const u16* A = (blockIdx.y < 8) ? A1 : A2;
    gemm_body<0,0>(A, W, bias, C, nullptr, nullptr, K, ldc);
}

// ---------------- 128x256 pipelined GEMM (round-3 proven 3-slot ring, 1 barrier/slice) ----
// used for N>=2048 GEMMs (qkv with fused V-transpose, ff1): best FLOP/staging ratio.
template<int ACT, int RES, int DUAL, int VT>
__global__ __launch_bounds__(512, 2) void gemm_p(const u16* __restrict__ A1, const u16* __restrict__ A2,
                                                 const u16* __restrict__ W, const u16* __restrict__ bias,
                                                 u16* __restrict__ C, const u16* __restrict__ res,
                                                 u16* __restrict__ vtp, int K, int ldc){
    __shared__ __align__(16) short lds[36864];   // 3 * (4096 A + 8192 B) shorts = 72 KiB
    const int t = threadIdx.x;
    const int w = t >> 6, lane = t & 63;
    const int quad = lane >> 4, l16 = lane & 15;
    const int wm = w >> 2, wn = w & 3;           // 2 x 4 waves
    const int m0 = blockIdx.x * 128;
    const int n0 = blockIdx.y * 256;
    const u16* A = (DUAL && blockIdx.y >= 4) ? A2 : A1;

    const int srow = t >> 2;                     // 0..127
    const int gl   = (t & 3) ^ ((t >> 3) & 3);
    const u16* Ag = A + (size_t)(m0 + srow)*K + gl*8;
    const u16* Bg = W + (size_t)(n0 + srow)*K + gl*8;
    const size_t rstep = (size_t)128 * K;        // B rows 128..255 (row+128 -> same XOR)
    short* ldst = &lds[t*8];

    const int koff = (quad ^ ((l16 >> 1) & 3)) * 8;
    const int aoff = (wm*64 + l16)*32 + koff;
    const int boff = 4096 + (wn*64 + l16)*32 + koff;

    f32x4 acc[4][4] = {};
    const int NS = K >> 5;

    // prologue: slice 0 -> slot0, slice 1 -> slot1
    gload_lds16(Ag,              ldst);
    gload_lds16(Bg,              ldst + 4096);
    gload_lds16(Bg + rstep,      ldst + 8192);
    gload_lds16(Ag + 32,         ldst + 12288);
    gload_lds16(Bg + 32,         ldst + 12288 + 4096);
    gload_lds16(Bg + rstep + 32, ldst + 12288 + 8192);
    asm volatile("s_waitcnt vmcnt(3)" ::: "memory");       // slice 0 landed
    __builtin_amdgcn_s_barrier();
    asm volatile("" ::: "memory");

    int slot = 0, slot2 = 2;
    for (int s = 0; s < NS; ++s){
        const int sb = slot * 12288;
        const short* Ab = &lds[sb + aoff];
        const short* Bb = &lds[sb + boff];
        bf16x8 av[4], bv[4];
#pragma unroll
        for (int i=0;i<4;i++) av[i] = *(const bf16x8*)(Ab + i*512);
#pragma unroll
        for (int j=0;j<4;j++) bv[j] = *(const bf16x8*)(Bb + j*512);
        const int prefetch = (s + 2 < NS);
        if (prefetch){
            const u16* Ap = Ag + (size_t)(s+2)*32;
            const u16* Bp = Bg + (size_t)(s+2)*32;
            short* ld2 = &lds[slot2*12288 + t*8];
            gload_lds16(Ap,         ld2);
            gload_lds16(Bp,         ld2 + 4096);
            gload_lds16(Bp + rstep, ld2 + 8192);
        }
        __builtin_amdgcn_s_setprio(1);
#pragma unroll
        for (int i=0;i<4;i++)
#pragma unroll
            for (int j=0;j<4;j++)
                acc[i][j] = __builtin_amdgcn_mfma_f32_16x16x32_bf16(av[i], bv[j], acc[i][j], 0,0,0);
        __builtin_amdgcn_s_setprio(0);
        if (prefetch) asm volatile("s_waitcnt vmcnt(3)" ::: "memory");   // s+1 landed
        else          asm volatile("s_waitcnt vmcnt(0)" ::: "memory");   // tail: cover s+1
        __builtin_amdgcn_s_barrier();
        asm volatile("" ::: "memory");

        slot  = (slot  == 2) ? 0 : slot  + 1;
        slot2 = (slot2 == 2) ? 0 : slot2 + 1;
    }

    // epilogue: C/D layout col=lane&15, row=quad*4+reg
    if (VT && n0 >= 2048){
#pragma unroll
        for (int i=0;i<4;i++){
            const int rowb = m0 + wm*64 + i*16 + quad*4;
            const int bq = rowb >> 9, sv = rowb & 511;
#pragma unroll
            for (int j=0;j<4;j++){
                const int col = n0 + wn*64 + j*16 + l16;
                const float bvv = b2f(bias[col]);
                const int hh = (col - 2048) >> 8;
                const int dd = (col - 2048) & 255;
                ushort4 ov;
                ov.x = f2b(acc[i][j][0] + bvv);
                ov.y = f2b(acc[i][j][1] + bvv);
                ov.z = f2b(acc[i][j][2] + bvv);
                ov.w = f2b(acc[i][j][3] + bvv);
                *(ushort4*)&vtp[(size_t)((bq*4 + hh)*HDD + dd)*SS + sv] = ov;
            }
        }
    } else {
#pragma unroll
        for (int i=0;i<4;i++){
            const int rowb = m0 + wm*64 + i*16 + quad*4;
#pragma unroll
            for (int j=0;j<4;j++){
                const int col = n0 + wn*64 + j*16 + l16;
                const float bvv = b2f(bias[col]);
#pragma unroll
                for (int r=0;r<4;r++){
                    float v = acc[i][j][r] + bvv;
                    if (RES) v += b2f(res[(size_t)(rowb + r)*ldc + col]);
                    if (ACT == 1) v = fmaxf(v, 0.0f);
                    C[(size_t)(rowb + r)*ldc + col] = f2b(v);
                }
            }
        }
    }
}

// ---------------- 128x128 pipelined GEMM (4 waves, 3-slot ring, 3 blocks/CU) ----------------
// used ONLY for N=1024 GEMMs (out-proj, ff2): grid 512 = 2 blocks/CU restores cross-block
// overlap that gemm_p's grid-256 (1/CU) lacks. For N>=2048 this variant LOSES (round-7
// measured: qkv 60.5 -> 72 us) because staging bytes + barriers per FLOP double.
template<int ACT, int RES, int DUAL, int VT>
__global__ __launch_bounds__(256, 3) void gemm_p128(const u16* __restrict__ A1, const u16* __restrict__ A2,
                                                    const u16* __restrict__ W, const u16* __restrict__ bias,
                                                    u16* __restrict__ C, const u16* __restrict__ res,
                                                    u16* __restrict__ vtp, int K, int ldc){
    __shared__ __align__(16) short lds[24576];   // 3 * (4096 A + 4096 B) shorts = 48 KiB
    const int t = threadIdx.x;
    const int w = t >> 6, lane = t & 63;
    const int quad = lane >> 4, l16 = lane & 15;
    const int wm = w >> 1, wn = w & 1;           // 2 x 2 waves
    const int m0 = blockIdx.x * 128;
    const int n0 = blockIdx.y * 128;
    const u16* A = (DUAL && blockIdx.y >= 8) ? A2 : A1;

    const int gl = (t & 3) ^ ((t >> 3) & 3);     // pre-swizzled k-granule
    const u16* Ag = A + (size_t)(m0 + (t>>2))*K + gl*8;
    const u16* Bg = W + (size_t)(n0 + (t>>2))*K + gl*8;
    const size_t rstep = (size_t)64 * K;         // rows 64..127 (row+64 -> same XOR)
    short* ldst = &lds[t*8];

    const int koff = (quad ^ ((l16 >> 1) & 3)) * 8;
    const int aoff = (wm*64 + l16)*32 + koff;
    const int boff = 4096 + (wn*64 + l16)*32 + koff;

    f32x4 acc[4][4] = {};
    const int NS = K >> 5;

    auto STG = [&](int ss, int sb){              // 4 loads: A rows [0..64),[64..128), B same
        const size_t ko = (size_t)ss*32;
        gload_lds16(Ag + ko,          ldst + sb);
        gload_lds16(Ag + rstep + ko,  ldst + sb + 2048);
        gload_lds16(Bg + ko,          ldst + sb + 4096);
        gload_lds16(Bg + rstep + ko,  ldst + sb + 6144);
    };

    // prologue: slice 0 -> slot0, slice 1 -> slot1
    STG(0, 0); STG(1, 8192);
    asm volatile("s_waitcnt vmcnt(4)" ::: "memory");       // slice 0 landed
    __builtin_amdgcn_s_barrier();
    asm volatile("" ::: "memory");

    int slot = 0, slot2 = 2;
    for (int s = 0; s < NS; ++s){
        const int sb = slot * 8192;
        const short* Ab = &lds[sb + aoff];
        const short* Bb = &lds[sb + boff];
        bf16x8 av[4], bv[4];
#pragma unroll
        for (int i=0;i<4;i++) av[i] = *(const bf16x8*)(Ab + i*512);
#pragma unroll
        for (int j=0;j<4;j++) bv[j] = *(const bf16x8*)(Bb + j*512);
        const int prefetch = (s + 2 < NS);
        if (prefetch) STG(s+2, slot2*8192);
        __builtin_amdgcn_s_setprio(1);
#pragma unroll
        for (int i=0;i<4;i++)
#pragma unroll
            for (int j=0;j<4;j++)
                acc[i][j] = __builtin_amdgcn_mfma_f32_16x16x32_bf16(av[i], bv[j], acc[i][j], 0,0,0);
        __builtin_amdgcn_s_setprio(0);
        if (prefetch) asm volatile("s_waitcnt vmcnt(4)" ::: "memory");   // s+1 landed
        else          asm volatile("s_waitcnt vmcnt(0)" ::: "memory");   // tail: cover s+1
        __builtin_amdgcn_s_barrier();
        asm volatile("" ::: "memory");

        slot  = (slot  == 2) ? 0 : slot  + 1;
        slot2 = (slot2 == 2) ? 0 : slot2 + 1;
    }

    // epilogue: C/D layout col=lane&15, row=quad*4+reg
    if (VT && n0 >= 2048){
#pragma unroll
        for (int i=0;i<4;i++){
            const int rowb = m0 + wm*64 + i*16 + quad*4;
            const int bq = rowb >> 9, sv = rowb & 511;
#pragma unroll
            for (int j=0;j<4;j++){
                const int col = n0 + wn*64 + j*16 + l16;
                const float bvv = b2f(bias[col]);
                const int hh = (col - 2048) >> 8;
                const int dd = (col - 2048) & 255;
                ushort4 ov;
                ov.x = f2b(acc[i][j][0] + bvv);
                ov.y = f2b(acc[i][j][1] + bvv);
                ov.z = f2b(acc[i][j][2] + bvv);
                ov.w = f2b(acc[i][j][3] + bvv);
                *(ushort4*)&vtp[(size_t)((bq*4 + hh)*HDD + dd)*SS + sv] = ov;
            }
        }
    } else {
#pragma unroll
        for (int i=0;i<4;i++){
            const int rowb = m0 + wm*64 + i*16 + quad*4;
#pragma unroll
            for (int j=0;j<4;j++){
                const int col = n0 + wn*64 + j*16 + l16;
                const float bvv = b2f(bias[col]);
#pragma unroll
                for (int r=0;r<4;r++){
                    float v = acc[i][j][r] + bvv;
                    if (RES) v += b2f(res[(size_t)(rowb + r)*ldc + col]);
                    if (ACT == 1) v = fmaxf(v, 0.0f);
                    C[(size_t)(rowb + r)*ldc + col] = f2b(v);
                }
            }
        }
    }
}

// ---------------- V transpose (fallback path only) ----------------
__global__ __launch_bounds__(256) void vt_kernel(const u16* __restrict__ qkv, u16* __restrict__ vt){
    __shared__ __align__(16) u16 tile[64][72];
    const int bh = blockIdx.x, b = bh >> 2, h = bh & 3;
    const int s0 = blockIdx.y*64, d0 = blockIdx.z*64;
    const int t = threadIdx.x;
#pragma unroll
    for (int it=0; it<2; it++){
        const int u = it*256 + t;
        const int sl = u >> 3, dc = (u & 7)*8;
        *(uint4*)&tile[sl][dc] =
            *(const uint4*)(qkv + (size_t)(b*SS + s0 + sl)*3072 + 2*DD + h*HDD + d0 + dc);
    }
    __syncthreads();
#pragma unroll
    for (int it=0; it<2; it++){
        const int u = it*256 + t;
        const int dl = u >> 3, sc = (u & 7)*8;
        uint4 tv; u16* tmp = (u16*)&tv;
#pragma unroll
        for (int j=0;j<8;j++) tmp[j] = tile[sc+j][dl];
        *(uint4*)(vt + (size_t)(bh*HDD + d0 + dl)*SS + s0 + sc) = tv;
    }
}

// ---------------- flash attention (2-slot K/V ring, counted vmcnt, XCD-local grid) ----
__global__ __launch_bounds__(256) void flash_attn(const u16* __restrict__ qkv, const u16* __restrict__ vt,
                                                  u16* __restrict__ ao, const int causal){
    __shared__ __align__(16) short Kt[2][8192];
    __shared__ __align__(16) short Vs[2][8192];
    __shared__ __align__(16) short pbuf[4][16][40];
    const int bh = blockIdx.x;
    // heavy causal q-tiles first (load-balance the tail)
    const int qt = causal ? (gridDim.y - 1 - blockIdx.y) : blockIdx.y;
    const int b = bh >> 2, h = bh & 3;
    const int t = threadIdx.x, w = t >> 6, lane = t & 63;
    const int quad = lane >> 4, l16 = lane & 15;
    const int qbase = qt * 64;

    const u16* qp = qkv + (size_t)(b*SS + qbase + w*16 + l16)*3072 + h*HDD + quad*8;
    bf16x8 qf[8];
#pragma unroll
    for (int kc=0;kc<8;kc++) qf[kc] = *(const bf16x8*)(qp + kc*32);

    f32x4 o[16] = {};
    float mrow[4] = {-1e30f,-1e30f,-1e30f,-1e30f};
    float lrow[4] = {0.f,0.f,0.f,0.f};

    const int ntiles = causal ? (qbase/32 + 2) : (SS/32);
    const int myq = qbase + w*16 + quad*4;

    const u16* Kg = qkv + (size_t)(b*SS)*3072 + DD + h*HDD;
    const u16* Vg = vt + (size_t)bh*HDD*SS;
    const int keyl8 = t >> 5;
    const int kslot = t & 31;
    const int vrow4 = t >> 2;
    const int vslot = t & 3;

    // stage K/V tile kt2 into ring slot sl (same swizzled layout as before)
    auto stage = [&](int kt2, int sl){
        const int kv0s = kt2*32;
#pragma unroll
        for (int j=0;j<4;j++){
            const int keyl = j*8 + keyl8;
            const int ck   = kslot ^ keyl;
            gload_lds16(Kg + (size_t)(kv0s + keyl)*3072 + ck*8, &Kt[sl][j*2048 + t*8]);
            const int d  = j*64 + vrow4;
            const int cv = vslot ^ (d&3) ^ ((d>>2)&3);
            gload_lds16(Vg + (size_t)d*SS + kv0s + cv*8, &Vs[sl][j*2048 + t*8]);
        }
    };

    stage(0, 0);
    for (int kt=0; kt<ntiles; kt++){
        const int kv0 = kt*32;
        const int sl = kt & 1;
        if (kt + 1 < ntiles){
            stage(kt+1, sl^1);
            asm volatile("s_waitcnt vmcnt(8)" ::: "memory");   // tile kt landed; kt+1 in flight
        } else {
            asm volatile("s_waitcnt vmcnt(0)" ::: "memory");   // tail drain
        }
        __builtin_amdgcn_s_barrier();                          // tile kt visible to all
        asm volatile("" ::: "memory");

        f32x4 sc0 = {0.f,0.f,0.f,0.f}, sc1 = {0.f,0.f,0.f,0.f};
#pragma unroll
        for (int kk=0;kk<8;kk++){
            const int ch = kk*4 + quad;
            sc0 = __builtin_amdgcn_mfma_f32_16x16x32_bf16(qf[kk],
                    *(const bf16x8*)&Kt[sl][l16*256 + (ch ^ l16)*8], sc0, 0,0,0);
            sc1 = __builtin_amdgcn_mfma_f32_16x16x32_bf16(qf[kk],
                    *(const bf16x8*)&Kt[sl][(16+l16)*256 + (ch ^ (16+l16))*8], sc1, 0,0,0);
        }
#pragma unroll
        for (int r=0;r<4;r++){
            float a0 = sc0[r]*0.0625f, a1 = sc1[r]*0.0625f;
            if (causal){
                if (kv0 + l16 > myq + r)      a0 = -1e9f;
                if (kv0 + 16 + l16 > myq + r) a1 = -1e9f;
            }
            float tm = fmaxf(a0,a1);
            tm = fmaxf(tm, __shfl_xor(tm,1)); tm = fmaxf(tm, __shfl_xor(tm,2));
            tm = fmaxf(tm, __shfl_xor(tm,4)); tm = fmaxf(tm, __shfl_xor(tm,8));
            const float mnew  = fmaxf(mrow[r], tm);
            const float alpha = __expf(mrow[r] - mnew);
            const float p0 = __expf(a0 - mnew), p1 = __expf(a1 - mnew);
            float rs = p0 + p1;
            rs += __shfl_xor(rs,1); rs += __shfl_xor(rs,2);
            rs += __shfl_xor(rs,4); rs += __shfl_xor(rs,8);
            lrow[r] = lrow[r]*alpha + rs;
            mrow[r] = mnew;
#pragma unroll
            for (int dt=0;dt<16;dt++) o[dt][r] *= alpha;
            pbuf[w][quad*4+r][l16]      = (short)f2b(p0);
            pbuf[w][quad*4+r][16 + l16] = (short)f2b(p1);
        }
        asm volatile("s_waitcnt lgkmcnt(0)" ::: "memory");     // own-wave pbuf writes retired

        const bf16x8 pf = *(const bf16x8*)&pbuf[w][l16][quad*8];
#pragma unroll
        for (int dt=0;dt<16;dt++){
            const int d = dt*16 + l16;
            o[dt] = __builtin_amdgcn_mfma_f32_16x16x32_bf16(pf,
                      *(const bf16x8*)&Vs[sl][d*32 + ((quad ^ (d&3) ^ ((d>>2)&3)))*8], o[dt], 0,0,0);
        }
        asm volatile("s_waitcnt lgkmcnt(0)" ::: "memory");     // slot reads retired
        __builtin_amdgcn_s_barrier();                          // safe to overwrite slot sl^1
        asm volatile("" ::: "memory");
    }
#pragma unroll
    for (int r=0;r<4;r++){
        const size_t row = (size_t)(b*SS + myq + r);
        const float inv = 1.0f / lrow[r];
#pragma unroll
        for (int dt=0;dt<16;dt++)
            ao[row*DD + h*HDD + dt*16 + l16] = f2b(o[dt][r]*inv);
    }
}

// ---------------- LayerNorm over pre-summed y, writes h ----------------
__global__ __launch_bounds__(256) void ln_kernel(u16* __restrict__ h, const u16* __restrict__ y,
                                                 const void* __restrict__ lnw, const void* __restrict__ lnb,
                                                 size_t off, const int* __restrict__ flag){
    const int f = flag[0];
    const int m = blockIdx.x, t = threadIdx.x;
    __shared__ float red[8];
    const ushort4 yv = *(const ushort4*)&y[(size_t)m*DD + t*4];
    float vv[4]; float sum = 0.f;
    vv[0] = b2f(yv.x); vv[1] = b2f(yv.y); vv[2] = b2f(yv.z); vv[3] = b2f(yv.w);
#pragma unroll
    for (int j=0;j<4;j++) sum += vv[j];
    for (int o2=1; o2<64; o2<<=1) sum += __shfl_xor(sum, o2);
    if ((t&63)==0) red[t>>6] = sum;
    __syncthreads();
    const float mean = (red[0]+red[1]+red[2]+red[3]) * (1.f/DD);
    float vs = 0.f;
#pragma unroll
    for (int j=0;j<4;j++){ const float d = vv[j]-mean; vs += d*d; }
    for (int o2=1; o2<64; o2<<=1) vs += __shfl_xor(vs, o2);
    if ((t&63)==0) red[4 + (t>>6)] = vs;
    __syncthreads();
    const float var = (red[4]+red[5]+red[6]+red[7]) * (1.f/DD);
    const float rstd = rsqrtf(var + 1e-5f);
    ushort4 ov;
    ov.x = f2b((vv[0]-mean)*rstd*ldin(lnw, off+t*4+0, f) + ldin(lnb, off+t*4+0, f));
    ov.y = f2b((vv[1]-mean)*rstd*ldin(lnw, off+t*4+1, f) + ldin(lnb, off+t*4+1, f));
    ov.z = f2b((vv[2]-mean)*rstd*ldin(lnw, off+t*4+2, f) + ldin(lnb, off+t*4+2, f));
    ov.w = f2b((vv[3]-mean)*rstd*ldin(lnw, off+t*4+3, f) + ldin(lnb, off+t*4+3, f));
    *(ushort4*)&h[(size_t)m*DD + t*4] = ov;
}

// ---------------- output head ----------------
__global__ __launch_bounds__(256) void final_kernel(const u16* __restrict__ p1, const void* __restrict__ w2,
                                                    const void* __restrict__ b2p, const int* __restrict__ basis,
                                                    void* __restrict__ out, const int* __restrict__ flag){
    const int f = flag[0];
    const int blk = blockIdx.x;            // B*L
    const int b = blk / LL, l = blk % LL;
    const int t = threadIdx.x;
    __shared__ float red[4];
    const ushort2 pv = *(const ushort2*)&p1[(size_t)(b*SS + l + 1)*HIDD + t*2];
    float acc;
    {
        float v0 = b2f(pv.x); v0 = v0 >= 0.f ? v0 : 0.01f*v0;
        float v1 = b2f(pv.y); v1 = v1 >= 0.f ? v1 : 0.01f*v1;
        acc = v0 * ldin(w2, t*2+0, f) + v1 * ldin(w2, t*2+1, f);
    }
    for (int off=1; off<64; off<<=1) acc += __shfl_xor(acc, off);
    if ((t & 63) == 0) red[t>>6] = acc;
    __syncthreads();
    if (t == 0){
        const float r = red[0]+red[1]+red[2]+red[3] + ldin(b2p, 0, f);
        const float v = (l < basis[b]) ? r : 0.0f;
        if (f) ((float*)out)[blk] = v;
        else   ((u16*)out)[blk] = f2b(v);
    }
}

extern "C" void kernel_launch(void* const* d_in, const int* in_sizes, int n_in,
                              void* d_out, int out_size, void* d_ws, size_t ws_size,
                              hipStream_t stream){
    const void* gs       = d_in[0];
    const void* prev     = d_in[1];
    const void* cur      = d_in[2];
    const void* target   = d_in[3];
    const void* bos      = d_in[4];
    const void* inp_w1   = d_in[5];
    const void* inp_b1   = d_in[6];
    const void* inp_w2   = d_in[7];
    const void* inp_b2   = d_in[8];
    const void* sa_qkv_w = d_in[9];
    const void* sa_qkv_b = d_in[10];
    const void* sa_out_w = d_in[11];
    const void* sa_out_b = d_in[12];
    const void* ca_qkv_w = d_in[13];
    const void* ca_qkv_b = d_in[14];
    const void* ca_out_w = d_in[15];
    const void* ca_out_b = d_in[16];
    const void* ln_w     = d_in[17];
    const void* ln_b     = d_in[18];
    const void* ff_w1    = d_in[19];
    const void* ff_b1    = d_in[20];
    const void* ff_w2    = d_in[21];
    const void* ff_b2    = d_in[22];
    const void* proj_w1  = d_in[23];
    const void* proj_b1  = d_in[24];
    const void* proj_w2  = d_in[25];
    const void* proj_b2  = d_in[26];
    const int*  basis    = (const int*)d_in[27];

    size_t off = 0;
    auto carve = [&](size_t bytes)->void*{
        void* p = (char*)d_ws + off;
        off += (bytes + 255) & ~(size_t)255;
        return p;
    };
    // common activation buffers (~118.6 MB)
    int*   flag = (int*)  carve(256);
    u16*   qkv  = (u16*)  carve((size_t)MTOK*3*DD*2);   // also U / ff1
    u16*   h    = (u16*)  carve((size_t)MTOK*DD*2);
    u16*   mem  = (u16*)  carve((size_t)MTOK*DD*2);
    u16*   ao   = (u16*)  carve((size_t)MTOK*DD*2);
    u16*   vty  = (u16*)  carve((size_t)MTOK*DD*2);     // vt / y / p1
    float* pe   = (float*)carve((size_t)SS*HIDD*4);
    u16* U  = qkv;
    u16* vt = vty;
    u16* y  = vty;

    // full-preconvert weight region (~77.1 MB)
    const size_t NW_TOTAL = 38535168, NB_TOTAL = 34816;
    const bool full = (ws_size >= off + ((NW_TOTAL*2+255)&~(size_t)255) + ((NB_TOTAL*2+255)&~(size_t)255));

    detect_kernel<<<dim3(1), 64, 0, stream>>>((const u16*)ln_w, flag);
    pe_kernel    <<<dim3(SS*HIDD/256),  256, 0, stream>>>(pe);
    inp_u_kernel <<<dim3(MTOK*HIDD/256),256, 0, stream>>>(bos, target, inp_w1, inp_b1, U, flag);

    if (full){
        u16* wbuf = (u16*)carve(NW_TOTAL*2);
        u16* bbuf = (u16*)carve(NB_TOTAL*2);
        // weight-region element offsets
        u16* w_saqkv = wbuf + 0;          // 3 x 3145728
        u16* w_saout = wbuf + 9437184;    // 3 x 1048576
        u16* w_caqkv = wbuf + 12582912;   // 3 x 3145728
        u16* w_caout = wbuf + 22020096;   // 3 x 1048576
        u16* w_ff1   = wbuf + 25165824;   // 3 x 2097152
        u16* w_ff2   = wbuf + 31457280;   // 3 x 2097152
        u16* w_inp2  = wbuf + 37748736;   // 262144
        u16* w_proj1 = wbuf + 38010880;   // 524288
        u16* b_saqkv = bbuf + 0;          // 3 x 3072
        u16* b_saout = bbuf + 9216;       // 3 x 1024
        u16* b_caqkv = bbuf + 12288;      // 3 x 3072
        u16* b_caout = bbuf + 21504;      // 3 x 1024
        u16* b_ff1   = bbuf + 24576;      // 3 x 2048
        u16* b_ff2   = bbuf + 30720;      // 3 x 1024
        u16* b_inp2  = bbuf + 33792;      // 512
        u16* b_proj1 = bbuf + 34304;      // 512

        // all weight conversions in ONE dispatch (8 jobs, blockIdx.y = job)
        WJobs jobs;
        jobs.j[0] = { inp_w2,   inp_b2,   w_inp2,  b_inp2,  HIDD*HIDD, HIDD   };
        jobs.j[1] = { sa_qkv_w, sa_qkv_b, w_saqkv, b_saqkv, 3*3*DD*DD, 3*3*DD };
        jobs.j[2] = { sa_out_w, sa_out_b, w_saout, b_saout, 3*DD*DD,   3*DD   };
        jobs.j[3] = { ca_qkv_w, ca_qkv_b, w_caqkv, b_caqkv, 3*3*DD*DD, 3*3*DD };
        jobs.j[4] = { ca_out_w, ca_out_b, w_caout, b_caout, 3*DD*DD,   3*DD   };
        jobs.j[5] = { ff_w1,    ff_b1,    w_ff1,   b_ff1,   3*DFFF*DD, 3*DFFF };
        jobs.j[6] = { ff_w2,    ff_b2,    w_ff2,   b_ff2,   3*DD*DFFF, 3*DD   };
        jobs.j[7] = { proj_w1,  proj_b1,  w_proj1, b_proj1, HIDD*DD,   HIDD   };
        wconv8_kernel<<<dim3(512,8),256,0,stream>>>(jobs, flag);

        gemm_bt<0,0> <<<dim3(64,4),  256, 0, stream>>>(U, w_inp2, b_inp2, h, pe, nullptr, HIDD, DD);
        concat_kernel<<<dim3(MTOK*DD/256), 256, 0, stream>>>(gs, prev, cur, h, mem, flag);

        for (int l = 0; l < 3; l++){
            gemm_p<0,0,0,1>   <<<dim3(64,12),512,0,stream>>>(h, nullptr, w_saqkv + (size_t)l*3*DD*DD,
                                                             b_saqkv + l*3*DD, qkv, nullptr, vt, DD, 3*DD);
            flash_attn        <<<dim3(64,8),  256,0,stream>>>(qkv, vt, ao, 1);
            gemm_p128<0,1,0,0><<<dim3(64,8),  256,0,stream>>>(ao, nullptr, w_saout + (size_t)l*DD*DD,
                                                              b_saout + l*DD, y, h, nullptr, DD, DD);
            ln_kernel         <<<dim3(MTOK),  256,0,stream>>>(h, y, ln_w, ln_b, (size_t)(l*3+0)*DD, flag);

            gemm_p<0,0,1,1>   <<<dim3(64,12),512,0,stream>>>(h, mem, w_caqkv + (size_t)l*3*DD*DD,
                                                             b_caqkv + l*3*DD, qkv, nullptr, vt, DD, 3*DD);
            flash_attn        <<<dim3(64,8),  256,0,stream>>>(qkv, vt, ao, 0);
            gemm_p128<0,1,0,0><<<dim3(64,8),  256,0,stream>>>(ao, nullptr, w_caout + (size_t)l*DD*DD,
                                                              b_caout + l*DD, y, h, nullptr, DD, DD);
            ln_kernel         <<<dim3(MTOK),  256,0,stream>>>(h, y, ln_w, ln_b, (size_t)(l*3+1)*DD, flag);

            gemm_p<1,0,0,0>   <<<dim3(64,8), 512,0,stream>>>(h, nullptr, w_ff1 + (size_t)l*DFFF*DD,
                                                             b_ff1 + l*DFFF, qkv, nullptr, nullptr, DD, DFFF);
            gemm_p128<0,1,0,0><<<dim3(64,8), 256,0,stream>>>(qkv, nullptr, w_ff2 + (size_t)l*DD*DFFF,
                                                             b_ff2 + l*DD, y, h, nullptr, DFFF, DD);
            ln_kernel         <<<dim3(MTOK), 256,0,stream>>>(h, y, ln_w, ln_b, (size_t)(l*3+2)*DD, flag);
        }
        gemm_bt<0,0><<<dim3(64,4), 256,0,stream>>>(h, w_proj1, b_proj1, y, nullptr, nullptr, DD, HIDD);
        final_kernel<<<dim3(BB*LL),256,0,stream>>>(y, proj_w2, proj_b2, basis, d_out, flag);
    } else {
        // fallback: round-5 proven two-slot scheme (+ residual fusion & dual CA)
        u16* s0w = (u16*)carve((size_t)3*DD*DD*2);
        u16* s0b = (u16*)carve((size_t)4096*2);
        u16* s1w = (u16*)carve((size_t)3*DD*DD*2);
        u16* s1b = (u16*)carve((size_t)4096*2);
        const dim3 wcg(512);

        wconv_kernel<<<wcg,256,0,stream>>>(inp_w2, 0, inp_b2, 0, s0w, s0b, HIDD*HIDD, HIDD, flag);
        gemm_bt<0,0><<<dim3(64,4), 256,0,stream>>>(U, s0w, s0b, h, pe, nullptr, HIDD, DD);
        concat_kernel<<<dim3(MTOK*DD/256),256,0,stream>>>(gs, prev, cur, h, mem, flag);

        for (int l = 0; l < 3; l++){
            wconv_kernel<<<wcg,256,0,stream>>>(sa_qkv_w, (size_t)l*3*DD*DD, sa_qkv_b, (size_t)l*3*DD,
                                               s1w, s1b, 3*DD*DD, 3*DD, flag);
            gemm_bt<0,0><<<dim3(64,24),256,0,stream>>>(h, s1w, s1b, qkv, nullptr, nullptr, DD, 3*DD);
            vt_kernel   <<<dim3(64,8,4),256,0,stream>>>(qkv, vt);
            flash_attn  <<<dim3(64,8),  256,0,stream>>>(qkv, vt, ao, 1);
            wconv_kernel<<<wcg,256,0,stream>>>(sa_out_w, (size_t)l*DD*DD, sa_out_b, (size_t)l*DD,
                                               s0w, s0b, DD*DD, DD, flag);
            gemm_bt<0,1><<<dim3(64,8), 256,0,stream>>>(ao, s0w, s0b, y, nullptr, h, DD, DD);
            ln_kernel   <<<dim3(MTOK), 256,0,stream>>>(h, y, ln_w, ln_b, (size_t)(l*3+0)*DD, flag);

            wconv_kernel<<<wcg,256,0,stream>>>(ca_qkv_w, (size_t)l*3*DD*DD, ca_qkv_b, (size_t)l*3*DD,
                                               s1w, s1b, 3*DD*DD, 3*DD, flag);
            gemm_dual   <<<dim3(64,24),256,0,stream>>>(h, mem, s1w, s1b, qkv, DD, 3*DD);
            vt_kernel   <<<dim3(64,8,4),256,0,stream>>>(qkv, vt);
            flash_attn  <<<dim3(64,8),  256,0,stream>>>(qkv, vt, ao, 0);
            wconv_kernel<<<wcg,256,0,stream>>>(ca_out_w, (size_t)l*DD*DD, ca_out_b, (size_t)l*DD,
                                               s0w, s0b, DD*DD, DD, flag);
            gemm_bt<0,1><<<dim3(64,8), 256,0,stream>>>(ao, s0w, s0b, y, nullptr, h, DD, DD);
            ln_kernel   <<<dim3(MTOK), 256,0,stream>>>(h, y, ln_w, ln_b, (size_t)(l*3+1)*DD, flag);

            wconv_kernel<<<wcg,256,0,stream>>>(ff_w1, (size_t)l*DFFF*DD, ff_b1, (size_t)l*DFFF,
                                               s1w, s1b, DFFF*DD, DFFF, flag);
            gemm_bt<1,0><<<dim3(64,16),256,0,stream>>>(h, s1w, s1b, qkv, nullptr, nullptr, DD, DFFF);
            wconv_kernel<<<wcg,256,0,stream>>>(ff_w2, (size_t)l*DD*DFFF, ff_b2, (size_t)l*DD,
                                               s0w, s0b, DD*DFFF, DD, flag);
            gemm_bt<0,1><<<dim3(64,8), 256,0,stream>>>(qkv, s0w, s0b, y, nullptr, h, DFFF, DD);
            ln_kernel   <<<dim3(MTOK), 256,0,stream>>>(h, y, ln_w, ln_b, (size_t)(l*3+2)*DD, flag);
        }
        wconv_kernel<<<wcg,256,0,stream>>>(proj_w1, 0, proj_b1, 0, s1w, s1b, HIDD*DD, HIDD, flag);
        gemm_bt<0,0><<<dim3(64,4), 256,0,stream>>>(h, s1w, s1b, y, nullptr, nullptr, DD, HIDD);
        final_kernel<<<dim3(BB*LL),256,0,stream>>>(y, proj_w2, proj_b2, basis, d_out, flag);
    }
}

// Round 9
// 1411.654 us; speedup vs baseline: 1.0504x; 1.0233x over previous
//
#include <hip/hip_runtime.h>

typedef unsigned short u16;
typedef __attribute__((ext_vector_type(8))) short bf16x8;
typedef __attribute__((ext_vector_type(4))) float f32x4;

#define BB   16
#define LL   511
#define SS   512
#define DD   1024
#define HIDD 512
#define DFFF 2048
#define NHH  4
#define HDD  256
#define MTOK (BB*SS)   // 8192

__device__ __forceinline__ float b2f(u16 u){ return __uint_as_float(((unsigned)u)<<16); }
__device__ __forceinline__ u16 f2b(float f){
    unsigned x = __float_as_uint(f);
    return (u16)((x + 0x7fffu + ((x>>16)&1u)) >> 16);   // RNE
}
__device__ __forceinline__ float ldin(const void* p, size_t i, int f){
    return f ? ((const float*)p)[i] : b2f(((const u16*)p)[i]);
}
__device__ __forceinline__ void gload_lds16(const void* g, void* l){
    __builtin_amdgcn_global_load_lds((const __attribute__((address_space(1))) unsigned*)g,
                                     (__attribute__((address_space(3))) unsigned*)l, 16, 0, 0);
}

// ---------------- dtype detect ----------------
__global__ void detect_kernel(const u16* __restrict__ lnw, int* __restrict__ flag){
    if (threadIdx.x == 0 && blockIdx.x == 0) flag[0] = (lnw[0] == 0x3F80) ? 0 : 1;
}

// ---------------- weight (+bias) conversion into bf16 scratch ----------------
__global__ void wconv_kernel(const void* __restrict__ w, size_t woff,
                             const void* __restrict__ b, size_t boff,
                             u16* __restrict__ dw, u16* __restrict__ db,
                             int nw, int nb, const int* __restrict__ flag){
    const int f = flag[0];
    const int idx = blockIdx.x*256 + threadIdx.x;
    const int stride = gridDim.x * 256;
    if (f){
        const float* wf = (const float*)w + woff;
        const float* bf = (const float*)b + boff;
        for (int i = idx*4; i < nw; i += stride*4){
            const float4 v = *(const float4*)&wf[i];
            ushort4 o; o.x=f2b(v.x); o.y=f2b(v.y); o.z=f2b(v.z); o.w=f2b(v.w);
            *(ushort4*)&dw[i] = o;
        }
        for (int i = idx*4; i < nb; i += stride*4){
            const float4 v = *(const float4*)&bf[i];
            ushort4 o; o.x=f2b(v.x); o.y=f2b(v.y); o.z=f2b(v.z); o.w=f2b(v.w);
            *(ushort4*)&db[i] = o;
        }
    } else {
        const u16* wu = (const u16*)w + woff;
        const u16* bu = (const u16*)b + boff;
        for (int i = idx*4; i < nw; i += stride*4) *(ushort4*)&dw[i] = *(const ushort4*)&wu[i];
        for (int i = idx*4; i < nb; i += stride*4) *(ushort4*)&db[i] = *(const ushort4*)&bu[i];
    }
}

// batched variant: 8 conversion jobs in ONE dispatch (blockIdx.y = job).
// 16 elems (4 x float4) per thread per stride: 4 loads in flight -> 4x MLP vs the
// 1-load version that measured only 3.7 TB/s combined (MLP-bound, VALUBusy 5%).
struct WJob  { const void* w; const void* b; u16* dw; u16* db; int nw; int nb; };
struct WJobs { WJob j[8]; };
__global__ void wconv8_kernel(WJobs jobs, const int* __restrict__ flag){
    const int f = flag[0];
    const WJob J = jobs.j[blockIdx.y];
    const int idx = blockIdx.x*256 + threadIdx.x;
    const int stride = gridDim.x * 256;
    if (f){
        const float* wf = (const float*)J.w;
        const float* bf = (const float*)J.b;
        for (int i = idx*16; i < J.nw; i += stride*16){
            const float4 v0 = *(const float4*)&wf[i];
            const float4 v1 = *(const float4*)&wf[i+4];
            const float4 v2 = *(const float4*)&wf[i+8];
            const float4 v3 = *(const float4*)&wf[i+12];
            ushort4 o0, o1, o2, o3;
            o0.x=f2b(v0.x); o0.y=f2b(v0.y); o0.z=f2b(v0.z); o0.w=f2b(v0.w);
            o1.x=f2b(v1.x); o1.y=f2b(v1.y); o1.z=f2b(v1.z); o1.w=f2b(v1.w);
            o2.x=f2b(v2.x); o2.y=f2b(v2.y); o2.z=f2b(v2.z); o2.w=f2b(v2.w);
            o3.x=f2b(v3.x); o3.y=f2b(v3.y); o3.z=f2b(v3.z); o3.w=f2b(v3.w);
            *(ushort4*)&J.dw[i]    = o0;
            *(ushort4*)&J.dw[i+4]  = o1;
            *(ushort4*)&J.dw[i+8]  = o2;
            *(ushort4*)&J.dw[i+12] = o3;
        }
        for (int i = idx*4; i < J.nb; i += stride*4){
            const float4 v = *(const float4*)&bf[i];
            ushort4 o; o.x=f2b(v.x); o.y=f2b(v.y); o.z=f2b(v.z); o.w=f2b(v.w);
            *(ushort4*)&J.db[i] = o;
        }
    } else {
        const u16* wu = (const u16*)J.w;
        const u16* bu = (const u16*)J.b;
        for (int i = idx*16; i < J.nw; i += stride*16){
            const uint4 v0 = *(const uint4*)&wu[i];
            const uint4 v1 = *(const uint4*)&wu[i+8];
            *(uint4*)&J.dw[i]   = v0;
            *(uint4*)&J.dw[i+8] = v1;
        }
        for (int i = idx*4; i < J.nb; i += stride*4) *(ushort4*)&J.db[i] = *(const ushort4*)&bu[i];
    }
}

// ---------------- positional encoding ----------------
__global__ void pe_kernel(float* __restrict__ pe){
    const int i = blockIdx.x*256 + threadIdx.x;       // < 512*512
    const int s = i >> 9, c = i & 511;
    const float div = expf(-(float)(c & ~1) * (logf(10000.0f)/512.0f));
    const float ang = (float)s * div;
    pe[i] = (c & 1) ? cosf(ang) : sinf(ang);
}

// ---------------- input proj stage 1 ----------------
__global__ void inp_u_kernel(const void* __restrict__ bos, const void* __restrict__ target,
                             const void* __restrict__ w1, const void* __restrict__ b1,
                             u16* __restrict__ U, const int* __restrict__ flag){
    const int f = flag[0];
    const int i = blockIdx.x*256 + threadIdx.x;       // < MTOK*HIDD
    const int m = i >> 9, c = i & 511;
    const int b = m >> 9, s = m & 511;
    const float ts = (s == 0) ? ldin(bos, 0, f) : ldin(target, b*LL + s - 1, f);
    float v = ts * ldin(w1, c, f) + ldin(b1, c, f);
    U[i] = f2b(v >= 0.f ? v : 0.01f*v);
}

// ---------------- concat ----------------
__global__ void concat_kernel(const void* __restrict__ gs, const void* __restrict__ prev,
                              const void* __restrict__ cur, u16* __restrict__ tgt,
                              u16* __restrict__ mem, const int* __restrict__ flag){
    const int f = flag[0];
    const int i = blockIdx.x*256 + threadIdx.x;       // < MTOK*DD
    const int m = i >> 10, c = i & 1023;
    if (c < 512){
        mem[i] = f2b(ldin(gs, (size_t)m*512 + c, f));
    } else {
        const float pc = (c < 768) ? ldin(prev, (m>>9)*256 + (c-512), f)
                                   : ldin(cur,  (m>>9)*256 + (c-768), f);
        const u16 pb = f2b(pc);
        tgt[i] = pb; mem[i] = pb;
    }
}

// ---------------- MFMA GEMM core (m97 structure, 128x128 tile, BK=32) ----------------
// fallback path only
template<int ACT, int RES>
__device__ __forceinline__ void gemm_body(const u16* __restrict__ A, const u16* __restrict__ W,
                                          const u16* __restrict__ bias, u16* __restrict__ C,
                                          const float* __restrict__ pe, const u16* __restrict__ res,
                                          int K, int ldc){
    __shared__ __align__(16) short As[4096];   // 128 x 32
    __shared__ __align__(16) short Bs[4096];
    const int m0 = blockIdx.x * 128;
    const int n0 = blockIdx.y * 128;
    const int t  = threadIdx.x;
    const int w = t >> 6, lane = t & 63;
    const int quad = lane >> 4, l16 = lane & 15;
    const int wm = (w >> 1) * 64, wn = (w & 1) * 64;

    f32x4 acc[4][4] = {};

    const u16* Ag = A + (size_t)(m0 + (t>>2))*K + (t&3)*8;
    const u16* Wg = W + (size_t)(n0 + (t>>2))*K + (t&3)*8;
    short* Asd = &As[t*8];
    short* Bsd = &Bs[t*8];
    for (int k0 = 0; k0 < K; k0 += 32){
        __syncthreads();
        gload_lds16(Ag + k0,                 Asd);
        gload_lds16(Ag + (size_t)64*K + k0,  Asd + 2048);
        gload_lds16(Wg + k0,                 Bsd);
        gload_lds16(Wg + (size_t)64*K + k0,  Bsd + 2048);
        __syncthreads();
        bf16x8 af[4], bfr[4];
#pragma unroll
        for (int i=0;i<4;i++) af[i]  = *(const bf16x8*)&As[(wm + i*16 + l16)*32 + quad*8];
#pragma unroll
        for (int j=0;j<4;j++) bfr[j] = *(const bf16x8*)&Bs[(wn + j*16 + l16)*32 + quad*8];
#pragma unroll
        for (int i=0;i<4;i++)
#pragma unroll
            for (int j=0;j<4;j++)
                acc[i][j] = __builtin_amdgcn_mfma_f32_16x16x32_bf16(af[i], bfr[j], acc[i][j], 0,0,0);
    }
    // epilogue: C/D layout col=lane&15, row=quad*4+reg
#pragma unroll
    for (int i=0;i<4;i++){
        const int rowb = m0 + wm + i*16 + quad*4;
#pragma unroll
        for (int j=0;j<4;j++){
            const int col = n0 + wn + j*16 + l16;
            const float bv = b2f(bias[col]);
#pragma unroll
            for (int r=0;r<4;r++){
                float v = acc[i][j][r] + bv;
                if (pe) v += pe[((rowb + r) & (SS-1))*HIDD + col];
                if (RES) v += b2f(res[(size_t)(rowb + r)*ldc + col]);
                if (ACT == 1) v = fmaxf(v, 0.0f);
                C[(size_t)(rowb + r)*ldc + col] = f2b(v);
            }
        }
    }
}

template<int ACT, int RES>
__global__ __launch_bounds__(256) void gemm_bt(const u16* __restrict__ A, const u16* __restrict__ W,
                                               const u16* __restrict__ bias, u16* __restrict__ C,
                                               const float* __restrict__ pe, const u16* __restrict__ res,
                                               int K, int ldc){
    gemm_body<ACT,RES>(A, W, bias, C, pe, res, K, ldc);
}

// CA q (from A1=h, cols<1024) + kv (from A2=mem, cols>=1024) in one dispatch (fallback path)
__global__ __launch_bounds__(256) void gemm_dual(const u16* __restrict__ A1, const u16* __restrict__ A2,
                                                 const u16* __restrict__ W, const u16* __restrict__ bias,
                                                 u16* __restrict__ C, int K, int ldc){
    const u16* A = (blockIdx.y < 8) ? A1 : A2;
    gemm_body<0,0>(A, W, bias, C, nullptr, nullptr, K, ldc);
}

// ---------------- 128x256 pipelined GEMM (round-3 proven 3-slot ring, 1 barrier/slice) ----
// used for N>=2048 GEMMs (qkv with fused V-transpose, ff1): best FLOP/staging ratio.
template<int ACT, int RES, int DUAL, int VT>
__global__ __launch_bounds__(512, 2) void gemm_p(const u16* __restrict__ A1, const u16* __restrict__ A2,
                                                 const u16* __restrict__ W, const u16* __restrict__ bias,
                                                 u16* __restrict__ C, const u16* __restrict__ res,
                                                 u16* __restrict__ vtp, int K, int ldc){
    __shared__ __align__(16) short lds[36864];   // 3 * (4096 A + 8192 B) shorts = 72 KiB
    const int t = threadIdx.x;
    const int w = t >> 6, lane = t & 63;
    const int quad = lane >> 4, l16 = lane & 15;
    const int wm = w >> 2, wn = w & 3;           // 2 x 4 waves
    const int m0 = blockIdx.x * 128;
    const int n0 = blockIdx.y * 256;
    const u16* A = (DUAL && blockIdx.y >= 4) ? A2 : A1;

    const int srow = t >> 2;                     // 0..127
    const int gl   = (t & 3) ^ ((t >> 3) & 3);
    const u16* Ag = A + (size_t)(m0 + srow)*K + gl*8;
    const u16* Bg = W + (size_t)(n0 + srow)*K + gl*8;
    const size_t rstep = (size_t)128 * K;        // B rows 128..255 (row+128 -> same XOR)
    short* ldst = &lds[t*8];

    const int koff = (quad ^ ((l16 >> 1) & 3)) * 8;
    const int aoff = (wm*64 + l16)*32 + koff;
    const int boff = 4096 + (wn*64 + l16)*32 + koff;

    f32x4 acc[4][4] = {};
    const int NS = K >> 5;

    // prologue: slice 0 -> slot0, slice 1 -> slot1
    gload_lds16(Ag,              ldst);
    gload_lds16(Bg,              ldst + 4096);
    gload_lds16(Bg + rstep,      ldst + 8192);
    gload_lds16(Ag + 32,         ldst + 12288);
    gload_lds16(Bg + 32,         ldst + 12288 + 4096);
    gload_lds16(Bg + rstep + 32, ldst + 12288 + 8192);
    asm volatile("s_waitcnt vmcnt(3)" ::: "memory");       // slice 0 landed
    __builtin_amdgcn_s_barrier();
    asm volatile("" ::: "memory");

    int slot = 0, slot2 = 2;
    for (int s = 0; s < NS; ++s){
        const int sb = slot * 12288;
        const short* Ab = &lds[sb + aoff];
        const short* Bb = &lds[sb + boff];
        bf16x8 av[4], bv[4];
#pragma unroll
        for (int i=0;i<4;i++) av[i] = *(const bf16x8*)(Ab + i*512);
#pragma unroll
        for (int j=0;j<4;j++) bv[j] = *(const bf16x8*)(Bb + j*512);
        const int prefetch = (s + 2 < NS);
        if (prefetch){
            const u16* Ap = Ag + (size_t)(s+2)*32;
            const u16* Bp = Bg + (size_t)(s+2)*32;
            short* ld2 = &lds[slot2*12288 + t*8];
            gload_lds16(Ap,         ld2);
            gload_lds16(Bp,         ld2 + 4096);
            gload_lds16(Bp + rstep, ld2 + 8192);
        }
        __builtin_amdgcn_s_setprio(1);
#pragma unroll
        for (int i=0;i<4;i++)
#pragma unroll
            for (int j=0;j<4;j++)
                acc[i][j] = __builtin_amdgcn_mfma_f32_16x16x32_bf16(av[i], bv[j], acc[i][j], 0,0,0);
        __builtin_amdgcn_s_setprio(0);
        if (prefetch) asm volatile("s_waitcnt vmcnt(3)" ::: "memory");   // s+1 landed
        else          asm volatile("s_waitcnt vmcnt(0)" ::: "memory");   // tail: cover s+1
        __builtin_amdgcn_s_barrier();
        asm volatile("" ::: "memory");

        slot  = (slot  == 2) ? 0 : slot  + 1;
        slot2 = (slot2 == 2) ? 0 : slot2 + 1;
    }

    // epilogue: C/D layout col=lane&15, row=quad*4+reg
    if (VT && n0 >= 2048){
#pragma unroll
        for (int i=0;i<4;i++){
            const int rowb = m0 + wm*64 + i*16 + quad*4;
            const int bq = rowb >> 9, sv = rowb & 511;
#pragma unroll
            for (int j=0;j<4;j++){
                const int col = n0 + wn*64 + j*16 + l16;
                const float bvv = b2f(bias[col]);
                const int hh = (col - 2048) >> 8;
                const int dd = (col - 2048) & 255;
                ushort4 ov;
                ov.x = f2b(acc[i][j][0] + bvv);
                ov.y = f2b(acc[i][j][1] + bvv);
                ov.z = f2b(acc[i][j][2] + bvv);
                ov.w = f2b(acc[i][j][3] + bvv);
                *(ushort4*)&vtp[(size_t)((bq*4 + hh)*HDD + dd)*SS + sv] = ov;
            }
        }
    } else {
#pragma unroll
        for (int i=0;i<4;i++){
            const int rowb = m0 + wm*64 + i*16 + quad*4;
#pragma unroll
            for (int j=0;j<4;j++){
                const int col = n0 + wn*64 + j*16 + l16;
                const float bvv = b2f(bias[col]);
#pragma unroll
                for (int r=0;r<4;r++){
                    float v = acc[i][j][r] + bvv;
                    if (RES) v += b2f(res[(size_t)(rowb + r)*ldc + col]);
                    if (ACT == 1) v = fmaxf(v, 0.0f);
                    C[(size_t)(rowb + r)*ldc + col] = f2b(v);
                }
            }
        }
    }
}

// ---------------- 128x128 pipelined GEMM (4 waves, 3-slot ring, 3 blocks/CU) ----------------
// used for N<=1024 GEMMs (out-proj, ff2, inp w/ PE fusion, proj1): restores cross-block
// overlap for small-N grids. For N>=2048 this variant LOSES (round-7: qkv 60.5 -> 72 us).
template<int ACT, int RES, int DUAL, int VT, int PEF>
__global__ __launch_bounds__(256, 3) void gemm_p128(const u16* __restrict__ A1, const u16* __restrict__ A2,
                                                    const u16* __restrict__ W, const u16* __restrict__ bias,
                                                    u16* __restrict__ C, const u16* __restrict__ res,
                                                    u16* __restrict__ vtp, const float* __restrict__ pe,
                                                    int K, int ldc){
    __shared__ __align__(16) short lds[24576];   // 3 * (4096 A + 4096 B) shorts = 48 KiB
    const int t = threadIdx.x;
    const int w = t >> 6, lane = t & 63;
    const int quad = lane >> 4, l16 = lane & 15;
    const int wm = w >> 1, wn = w & 1;           // 2 x 2 waves
    const int m0 = blockIdx.x * 128;
    const int n0 = blockIdx.y * 128;
    const u16* A = (DUAL && blockIdx.y >= 8) ? A2 : A1;

    const int gl = (t & 3) ^ ((t >> 3) & 3);     // pre-swizzled k-granule
    const u16* Ag = A + (size_t)(m0 + (t>>2))*K + gl*8;
    const u16* Bg = W + (size_t)(n0 + (t>>2))*K + gl*8;
    const size_t rstep = (size_t)64 * K;         // rows 64..127 (row+64 -> same XOR)
    short* ldst = &lds[t*8];

    const int koff = (quad ^ ((l16 >> 1) & 3)) * 8;
    const int aoff = (wm*64 + l16)*32 + koff;
    const int boff = 4096 + (wn*64 + l16)*32 + koff;

    f32x4 acc[4][4] = {};
    const int NS = K >> 5;

    auto STG = [&](int ss, int sb){              // 4 loads: A rows [0..64),[64..128), B same
        const size_t ko = (size_t)ss*32;
        gload_lds16(Ag + ko,          ldst + sb);
        gload_lds16(Ag + rstep + ko,  ldst + sb + 2048);
        gload_lds16(Bg + ko,          ldst + sb + 4096);
        gload_lds16(Bg + rstep + ko,  ldst + sb + 6144);
    };

    // prologue: slice 0 -> slot0, slice 1 -> slot1
    STG(0, 0); STG(1, 8192);
    asm volatile("s_waitcnt vmcnt(4)" ::: "memory");       // slice 0 landed
    __builtin_amdgcn_s_barrier();
    asm volatile("" ::: "memory");

    int slot = 0, slot2 = 2;
    for (int s = 0; s < NS; ++s){
        const int sb = slot * 8192;
        const short* Ab = &lds[sb + aoff];
        const short* Bb = &lds[sb + boff];
        bf16x8 av[4], bv[4];
#pragma unroll
        for (int i=0;i<4;i++) av[i] = *(const bf16x8*)(Ab + i*512);
#pragma unroll
        for (int j=0;j<4;j++) bv[j] = *(const bf16x8*)(Bb + j*512);
        const int prefetch = (s + 2 < NS);
        if (prefetch) STG(s+2, slot2*8192);
        __builtin_amdgcn_s_setprio(1);
#pragma unroll
        for (int i=0;i<4;i++)
#pragma unroll
            for (int j=0;j<4;j++)
                acc[i][j] = __builtin_amdgcn_mfma_f32_16x16x32_bf16(av[i], bv[j], acc[i][j], 0,0,0);
        __builtin_amdgcn_s_setprio(0);
        if (prefetch) asm volatile("s_waitcnt vmcnt(4)" ::: "memory");   // s+1 landed
        else          asm volatile("s_waitcnt vmcnt(0)" ::: "memory");   // tail: cover s+1
        __builtin_amdgcn_s_barrier();
        asm volatile("" ::: "memory");

        slot  = (slot  == 2) ? 0 : slot  + 1;
        slot2 = (slot2 == 2) ? 0 : slot2 + 1;
    }

    // epilogue: C/D layout col=lane&15, row=quad*4+reg
    if (VT && n0 >= 2048){
#pragma unroll
        for (int i=0;i<4;i++){
            const int rowb = m0 + wm*64 + i*16 + quad*4;
            const int bq = rowb >> 9, sv = rowb & 511;
#pragma unroll
            for (int j=0;j<4;j++){
                const int col = n0 + wn*64 + j*16 + l16;
                const float bvv = b2f(bias[col]);
                const int hh = (col - 2048) >> 8;
                const int dd = (col - 2048) & 255;
                ushort4 ov;
                ov.x = f2b(acc[i][j][0] + bvv);
                ov.y = f2b(acc[i][j][1] + bvv);
                ov.z = f2b(acc[i][j][2] + bvv);
                ov.w = f2b(acc[i][j][3] + bvv);
                *(ushort4*)&vtp[(size_t)((bq*4 + hh)*HDD + dd)*SS + sv] = ov;
            }
        }
    } else {
#pragma unroll
        for (int i=0;i<4;i++){
            const int rowb = m0 + wm*64 + i*16 + quad*4;
#pragma unroll
            for (int j=0;j<4;j++){
                const int col = n0 + wn*64 + j*16 + l16;
                const float bvv = b2f(bias[col]);
#pragma unroll
                for (int r=0;r<4;r++){
                    float v = acc[i][j][r] + bvv;
                    if (PEF) v += pe[((rowb + r) & (SS-1))*HIDD + col];
                    if (RES) v += b2f(res[(size_t)(rowb + r)*ldc + col]);
                    if (ACT == 1) v = fmaxf(v, 0.0f);
                    C[(size_t)(rowb + r)*ldc + col] = f2b(v);
                }
            }
        }
    }
}

// ---------------- V transpose (fallback path only) ----------------
__global__ __launch_bounds__(256) void vt_kernel(const u16* __restrict__ qkv, u16* __restrict__ vt){
    __shared__ __align__(16) u16 tile[64][72];
    const int bh = blockIdx.x, b = bh >> 2, h = bh & 3;
    const int s0 = blockIdx.y*64, d0 = blockIdx.z*64;
    const int t = threadIdx.x;
#pragma unroll
    for (int it=0; it<2; it++){
        const int u = it*256 + t;
        const int sl = u >> 3, dc = (u & 7)*8;
        *(uint4*)&tile[sl][dc] =
            *(const uint4*)(qkv + (size_t)(b*SS + s0 + sl)*3072 + 2*DD + h*HDD + d0 + dc);
    }
    __syncthreads();
#pragma unroll
    for (int it=0; it<2; it++){
        const int u = it*256 + t;
        const int dl = u >> 3, sc = (u & 7)*8;
        uint4 tv; u16* tmp = (u16*)&tv;
#pragma unroll
        for (int j=0;j<8;j++) tmp[j] = tile[sc+j][dl];
        *(uint4*)(vt + (size_t)(bh*HDD + d0 + dl)*SS + s0 + sc) = tv;
    }
}

// ---------------- flash attention (2-slot K/V ring, counted vmcnt, XCD-local grid) ----
__global__ __launch_bounds__(256) void flash_attn(const u16* __restrict__ qkv, const u16* __restrict__ vt,
                                                  u16* __restrict__ ao, const int causal){
    __shared__ __align__(16) short Kt[2][8192];
    __shared__ __align__(16) short Vs[2][8192];
    __shared__ __align__(16) short pbuf[4][16][40];
    const int bh = blockIdx.x;
    // heavy causal q-tiles first (load-balance the tail)
    const int qt = causal ? (gridDim.y - 1 - blockIdx.y) : blockIdx.y;
    const int b = bh >> 2, h = bh & 3;
    const int t = threadIdx.x, w = t >> 6, lane = t & 63;
    const int quad = lane >> 4, l16 = lane & 15;
    const int qbase = qt * 64;

    const u16* qp = qkv + (size_t)(b*SS + qbase + w*16 + l16)*3072 + h*HDD + quad*8;
    bf16x8 qf[8];
#pragma unroll
    for (int kc=0;kc<8;kc++) qf[kc] = *(const bf16x8*)(qp + kc*32);

    f32x4 o[16] = {};
    float mrow[4] = {-1e30f,-1e30f,-1e30f,-1e30f};
    float lrow[4] = {0.f,0.f,0.f,0.f};

    const int ntiles = causal ? (qbase/32 + 2) : (SS/32);
    const int myq = qbase + w*16 + quad*4;

    const u16* Kg = qkv + (size_t)(b*SS)*3072 + DD + h*HDD;
    const u16* Vg = vt + (size_t)bh*HDD*SS;
    const int keyl8 = t >> 5;
    const int kslot = t & 31;
    const int vrow4 = t >> 2;
    const int vslot = t & 3;

    // stage K/V tile kt2 into ring slot sl (same swizzled layout as before)
    auto stage = [&](int kt2, int sl){
        const int kv0s = kt2*32;
#pragma unroll
        for (int j=0;j<4;j++){
            const int keyl = j*8 + keyl8;
            const int ck   = kslot ^ keyl;
            gload_lds16(Kg + (size_t)(kv0s + keyl)*3072 + ck*8, &Kt[sl][j*2048 + t*8]);
            const int d  = j*64 + vrow4;
            const int cv = vslot ^ (d&3) ^ ((d>>2)&3);
            gload_lds16(Vg + (size_t)d*SS + kv0s + cv*8, &Vs[sl][j*2048 + t*8]);
        }
    };

    stage(0, 0);
    for (int kt=0; kt<ntiles; kt++){
        const int kv0 = kt*32;
        const int sl = kt & 1;
        if (kt + 1 < ntiles){
            stage(kt+1, sl^1);
            asm volatile("s_waitcnt vmcnt(8)" ::: "memory");   // tile kt landed; kt+1 in flight
        } else {
            asm volatile("s_waitcnt vmcnt(0)" ::: "memory");   // tail drain
        }
        __builtin_amdgcn_s_barrier();                          // tile kt visible to all
        asm volatile("" ::: "memory");

        f32x4 sc0 = {0.f,0.f,0.f,0.f}, sc1 = {0.f,0.f,0.f,0.f};
#pragma unroll
        for (int kk=0;kk<8;kk++){
            const int ch = kk*4 + quad;
            sc0 = __builtin_amdgcn_mfma_f32_16x16x32_bf16(qf[kk],
                    *(const bf16x8*)&Kt[sl][l16*256 + (ch ^ l16)*8], sc0, 0,0,0);
            sc1 = __builtin_amdgcn_mfma_f32_16x16x32_bf16(qf[kk],
                    *(const bf16x8*)&Kt[sl][(16+l16)*256 + (ch ^ (16+l16))*8], sc1, 0,0,0);
        }
#pragma unroll
        for (int r=0;r<4;r++){
            float a0 = sc0[r]*0.0625f, a1 = sc1[r]*0.0625f;
            if (causal){
                if (kv0 + l16 > myq + r)      a0 = -1e9f;
                if (kv0 + 16 + l16 > myq + r) a1 = -1e9f;
            }
            float tm = fmaxf(a0,a1);
            tm = fmaxf(tm, __shfl_xor(tm,1)); tm = fmaxf(tm, __shfl_xor(tm,2));
            tm = fmaxf(tm, __shfl_xor(tm,4)); tm = fmaxf(tm, __shfl_xor(tm,8));
            const float mnew  = fmaxf(mrow[r], tm);
            const float alpha = __expf(mrow[r] - mnew);
            const float p0 = __expf(a0 - mnew), p1 = __expf(a1 - mnew);
            float rs = p0 + p1;
            rs += __shfl_xor(rs,1); rs += __shfl_xor(rs,2);
            rs += __shfl_xor(rs,4); rs += __shfl_xor(rs,8);
            lrow[r] = lrow[r]*alpha + rs;
            mrow[r] = mnew;
#pragma unroll
            for (int dt=0;dt<16;dt++) o[dt][r] *= alpha;
            pbuf[w][quad*4+r][l16]      = (short)f2b(p0);
            pbuf[w][quad*4+r][16 + l16] = (short)f2b(p1);
        }
        asm volatile("s_waitcnt lgkmcnt(0)" ::: "memory");     // own-wave pbuf writes retired

        const bf16x8 pf = *(const bf16x8*)&pbuf[w][l16][quad*8];
#pragma unroll
        for (int dt=0;dt<16;dt++){
            const int d = dt*16 + l16;
            o[dt] = __builtin_amdgcn_mfma_f32_16x16x32_bf16(pf,
                      *(const bf16x8*)&Vs[sl][d*32 + ((quad ^ (d&3) ^ ((d>>2)&3)))*8], o[dt], 0,0,0);
        }
        asm volatile("s_waitcnt lgkmcnt(0)" ::: "memory");     // slot reads retired
        __builtin_amdgcn_s_barrier();                          // safe to overwrite slot sl^1
        asm volatile("" ::: "memory");
    }
#pragma unroll
    for (int r=0;r<4;r++){
        const size_t row = (size_t)(b*SS + myq + r);
        const float inv = 1.0f / lrow[r];
#pragma unroll
        for (int dt=0;dt<16;dt++)
            ao[row*DD + h*HDD + dt*16 + l16] = f2b(o[dt][r]*inv);
    }
}

// ---------------- LayerNorm over pre-summed y, writes h ----------------
__global__ __launch_bounds__(256) void ln_kernel(u16* __restrict__ h, const u16* __restrict__ y,
                                                 const void* __restrict__ lnw, const void* __restrict__ lnb,
                                                 size_t off, const int* __restrict__ flag){
    const int f = flag[0];
    const int m = blockIdx.x, t = threadIdx.x;
    __shared__ float red[8];
    const ushort4 yv = *(const ushort4*)&y[(size_t)m*DD + t*4];
    float vv[4]; float sum = 0.f;
    vv[0] = b2f(yv.x); vv[1] = b2f(yv.y); vv[2] = b2f(yv.z); vv[3] = b2f(yv.w);
#pragma unroll
    for (int j=0;j<4;j++) sum += vv[j];
    for (int o2=1; o2<64; o2<<=1) sum += __shfl_xor(sum, o2);
    if ((t&63)==0) red[t>>6] = sum;
    __syncthreads();
    const float mean = (red[0]+red[1]+red[2]+red[3]) * (1.f/DD);
    float vs = 0.f;
#pragma unroll
    for (int j=0;j<4;j++){ const float d = vv[j]-mean; vs += d*d; }
    for (int o2=1; o2<64; o2<<=1) vs += __shfl_xor(vs, o2);
    if ((t&63)==0) red[4 + (t>>6)] = vs;
    __syncthreads();
    const float var = (red[4]+red[5]+red[6]+red[7]) * (1.f/DD);
    const float rstd = rsqrtf(var + 1e-5f);
    ushort4 ov;
    ov.x = f2b((vv[0]-mean)*rstd*ldin(lnw, off+t*4+0, f) + ldin(lnb, off+t*4+0, f));
    ov.y = f2b((vv[1]-mean)*rstd*ldin(lnw, off+t*4+1, f) + ldin(lnb, off+t*4+1, f));
    ov.z = f2b((vv[2]-mean)*rstd*ldin(lnw, off+t*4+2, f) + ldin(lnb, off+t*4+2, f));
    ov.w = f2b((vv[3]-mean)*rstd*ldin(lnw, off+t*4+3, f) + ldin(lnb, off+t*4+3, f));
    *(ushort4*)&h[(size_t)m*DD + t*4] = ov;
}

// ---------------- output head ----------------
__global__ __launch_bounds__(256) void final_kernel(const u16* __restrict__ p1, const void* __restrict__ w2,
                                                    const void* __restrict__ b2p, const int* __restrict__ basis,
                                                    void* __restrict__ out, const int* __restrict__ flag){
    const int f = flag[0];
    const int blk = blockIdx.x;            // B*L
    const int b = blk / LL, l = blk % LL;
    const int t = threadIdx.x;
    __shared__ float red[4];
    const ushort2 pv = *(const ushort2*)&p1[(size_t)(b*SS + l + 1)*HIDD + t*2];
    float acc;
    {
        float v0 = b2f(pv.x); v0 = v0 >= 0.f ? v0 : 0.01f*v0;
        float v1 = b2f(pv.y); v1 = v1 >= 0.f ? v1 : 0.01f*v1;
        acc = v0 * ldin(w2, t*2+0, f) + v1 * ldin(w2, t*2+1, f);
    }
    for (int off=1; off<64; off<<=1) acc += __shfl_xor(acc, off);
    if ((t & 63) == 0) red[t>>6] = acc;
    __syncthreads();
    if (t == 0){
        const float r = red[0]+red[1]+red[2]+red[3] + ldin(b2p, 0, f);
        const float v = (l < basis[b]) ? r : 0.0f;
        if (f) ((float*)out)[blk] = v;
        else   ((u16*)out)[blk] = f2b(v);
    }
}

extern "C" void kernel_launch(void* const* d_in, const int* in_sizes, int n_in,
                              void* d_out, int out_size, void* d_ws, size_t ws_size,
                              hipStream_t stream){
    const void* gs       = d_in[0];
    const void* prev     = d_in[1];
    const void* cur      = d_in[2];
    const void* target   = d_in[3];
    const void* bos      = d_in[4];
    const void* inp_w1   = d_in[5];
    const void* inp_b1   = d_in[6];
    const void* inp_w2   = d_in[7];
    const void* inp_b2   = d_in[8];
    const void* sa_qkv_w = d_in[9];
    const void* sa_qkv_b = d_in[10];
    const void* sa_out_w = d_in[11];
    const void* sa_out_b = d_in[12];
    const void* ca_qkv_w = d_in[13];
    const void* ca_qkv_b = d_in[14];
    const void* ca_out_w = d_in[15];
    const void* ca_out_b = d_in[16];
    const void* ln_w     = d_in[17];
    const void* ln_b     = d_in[18];
    const void* ff_w1    = d_in[19];
    const void* ff_b1    = d_in[20];
    const void* ff_w2    = d_in[21];
    const void* ff_b2    = d_in[22];
    const void* proj_w1  = d_in[23];
    const void* proj_b1  = d_in[24];
    const void* proj_w2  = d_in[25];
    const void* proj_b2  = d_in[26];
    const int*  basis    = (const int*)d_in[27];

    size_t off = 0;
    auto carve = [&](size_t bytes)->void*{
        void* p = (char*)d_ws + off;
        off += (bytes + 255) & ~(size_t)255;
        return p;
    };
    // common activation buffers (~118.6 MB)
    int*   flag = (int*)  carve(256);
    u16*   qkv  = (u16*)  carve((size_t)MTOK*3*DD*2);   // also U / ff1
    u16*   h    = (u16*)  carve((size_t)MTOK*DD*2);
    u16*   mem  = (u16*)  carve((size_t)MTOK*DD*2);
    u16*   ao   = (u16*)  carve((size_t)MTOK*DD*2);
    u16*   vty  = (u16*)  carve((size_t)MTOK*DD*2);     // vt / y / p1
    float* pe   = (float*)carve((size_t)SS*HIDD*4);
    u16* U  = qkv;
    u16* vt = vty;
    u16* y  = vty;

    // full-preconvert weight region (~77.1 MB)
    const size_t NW_TOTAL = 38535168, NB_TOTAL = 34816;
    const bool full = (ws_size >= off + ((NW_TOTAL*2+255)&~(size_t)255) + ((NB_TOTAL*2+255)&~(size_t)255));

    detect_kernel<<<dim3(1), 64, 0, stream>>>((const u16*)ln_w, flag);
    pe_kernel    <<<dim3(SS*HIDD/256),  256, 0, stream>>>(pe);
    inp_u_kernel <<<dim3(MTOK*HIDD/256),256, 0, stream>>>(bos, target, inp_w1, inp_b1, U, flag);

    if (full){
        u16* wbuf = (u16*)carve(NW_TOTAL*2);
        u16* bbuf = (u16*)carve(NB_TOTAL*2);
        // weight-region element offsets
        u16* w_saqkv = wbuf + 0;          // 3 x 3145728
        u16* w_saout = wbuf + 9437184;    // 3 x 1048576
        u16* w_caqkv = wbuf + 12582912;   // 3 x 3145728
        u16* w_caout = wbuf + 22020096;   // 3 x 1048576
        u16* w_ff1   = wbuf + 25165824;   // 3 x 2097152
        u16* w_ff2   = wbuf + 31457280;   // 3 x 2097152
        u16* w_inp2  = wbuf + 37748736;   // 262144
        u16* w_proj1 = wbuf + 38010880;   // 524288
        u16* b_saqkv = bbuf + 0;          // 3 x 3072
        u16* b_saout = bbuf + 9216;       // 3 x 1024
        u16* b_caqkv = bbuf + 12288;      // 3 x 3072
        u16* b_caout = bbuf + 21504;      // 3 x 1024
        u16* b_ff1   = bbuf + 24576;      // 3 x 2048
        u16* b_ff2   = bbuf + 30720;      // 3 x 1024
        u16* b_inp2  = bbuf + 33792;      // 512
        u16* b_proj1 = bbuf + 34304;      // 512

        // all weight conversions in ONE dispatch (8 jobs, blockIdx.y = job)
        WJobs jobs;
        jobs.j[0] = { inp_w2,   inp_b2,   w_inp2,  b_inp2,  HIDD*HIDD, HIDD   };
        jobs.j[1] = { sa_qkv_w, sa_qkv_b, w_saqkv, b_saqkv, 3*3*DD*DD, 3*3*DD };
        jobs.j[2] = { sa_out_w, sa_out_b, w_saout, b_saout, 3*DD*DD,   3*DD   };
        jobs.j[3] = { ca_qkv_w, ca_qkv_b, w_caqkv, b_caqkv, 3*3*DD*DD, 3*3*DD };
        jobs.j[4] = { ca_out_w, ca_out_b, w_caout, b_caout, 3*DD*DD,   3*DD   };
        jobs.j[5] = { ff_w1,    ff_b1,    w_ff1,   b_ff1,   3*DFFF*DD, 3*DFFF };
        jobs.j[6] = { ff_w2,    ff_b2,    w_ff2,   b_ff2,   3*DD*DFFF, 3*DD   };
        jobs.j[7] = { proj_w1,  proj_b1,  w_proj1, b_proj1, HIDD*DD,   HIDD   };
        wconv8_kernel<<<dim3(512,8),256,0,stream>>>(jobs, flag);

        gemm_p128<0,0,0,0,1><<<dim3(64,4),256,0,stream>>>(U, nullptr, w_inp2, b_inp2, h,
                                                          nullptr, nullptr, pe, HIDD, DD);
        concat_kernel<<<dim3(MTOK*DD/256), 256, 0, stream>>>(gs, prev, cur, h, mem, flag);

        for (int l = 0; l < 3; l++){
            gemm_p<0,0,0,1>     <<<dim3(64,12),512,0,stream>>>(h, nullptr, w_saqkv + (size_t)l*3*DD*DD,
                                                               b_saqkv + l*3*DD, qkv, nullptr, vt, DD, 3*DD);
            flash_attn          <<<dim3(64,8),  256,0,stream>>>(qkv, vt, ao, 1);
            gemm_p128<0,1,0,0,0><<<dim3(64,8),  256,0,stream>>>(ao, nullptr, w_saout + (size_t)l*DD*DD,
                                                                b_saout + l*DD, y, h, nullptr, nullptr, DD, DD);
            ln_kernel           <<<dim3(MTOK),  256,0,stream>>>(h, y, ln_w, ln_b, (size_t)(l*3+0)*DD, flag);

            gemm_p<0,0,1,1>     <<<dim3(64,12),512,0,stream>>>(h, mem, w_caqkv + (size_t)l*3*DD*DD,
                                                               b_caqkv + l*3*DD, qkv, nullptr, vt, DD, 3*DD);
            flash_attn          <<<dim3(64,8),  256,0,stream>>>(qkv, vt, ao, 0);
            gemm_p128<0,1,0,0,0><<<dim3(64,8),  256,0,stream>>>(ao, nullptr, w_caout + (size_t)l*DD*DD,
                                                                b_caout + l*DD, y, h, nullptr, nullptr, DD, DD);
            ln_kernel           <<<dim3(MTOK),  256,0,stream>>>(h, y, ln_w, ln_b, (size_t)(l*3+1)*DD, flag);

            gemm_p<1,0,0,0>     <<<dim3(64,8), 512,0,stream>>>(h, nullptr, w_ff1 + (size_t)l*DFFF*DD,
                                                               b_ff1 + l*DFFF, qkv, nullptr, nullptr, DD, DFFF);
            gemm_p128<0,1,0,0,0><<<dim3(64,8), 256,0,stream>>>(qkv, nullptr, w_ff2 + (size_t)l*DD*DFFF,
                                                               b_ff2 + l*DD, y, h, nullptr, nullptr, DFFF, DD);
            ln_kernel           <<<dim3(MTOK), 256,0,stream>>>(h, y, ln_w, ln_b, (size_t)(l*3+2)*DD, flag);
        }
        gemm_p128<0,0,0,0,0><<<dim3(64,4),256,0,stream>>>(h, nullptr, w_proj1, b_proj1, y,
                                                          nullptr, nullptr, nullptr, DD, HIDD);
        final_kernel<<<dim3(BB*LL),256,0,stream>>>(y, proj_w2, proj_b2, basis, d_out, flag);
    } else {
        // fallback: round-5 proven two-slot scheme (+ residual fusion & dual CA)
        u16* s0w = (u16*)carve((size_t)3*DD*DD*2);
        u16* s0b = (u16*)carve((size_t)4096*2);
        u16* s1w = (u16*)carve((size_t)3*DD*DD*2);
        u16* s1b = (u16*)carve((size_t)4096*2);
        const dim3 wcg(512);

        wconv_kernel<<<wcg,256,0,stream>>>(inp_w2, 0, inp_b2, 0, s0w, s0b, HIDD*HIDD, HIDD, flag);
        gemm_bt<0,0><<<dim3(64,4), 256,0,stream>>>(U, s0w, s0b, h, pe, nullptr, HIDD, DD);
        concat_kernel<<<dim3(MTOK*DD/256),256,0,stream>>>(gs, prev, cur, h, mem, flag);

        for (int l = 0; l < 3; l++){
            wconv_kernel<<<wcg,256,0,stream>>>(sa_qkv_w, (size_t)l*3*DD*DD, sa_qkv_b, (size_t)l*3*DD,
                                               s1w, s1b, 3*DD*DD, 3*DD, flag);
            gemm_bt<0,0><<<dim3(64,24),256,0,stream>>>(h, s1w, s1b, qkv, nullptr, nullptr, DD, 3*DD);
            vt_kernel   <<<dim3(64,8,4),256,0,stream>>>(qkv, vt);
            flash_attn  <<<dim3(64,8),  256,0,stream>>>(qkv, vt, ao, 1);
            wconv_kernel<<<wcg,256,0,stream>>>(sa_out_w, (size_t)l*DD*DD, sa_out_b, (size_t)l*DD,
                                               s0w, s0b, DD*DD, DD, flag);
            gemm_bt<0,1><<<dim3(64,8), 256,0,stream>>>(ao, s0w, s0b, y, nullptr, h, DD, DD);
            ln_kernel   <<<dim3(MTOK), 256,0,stream>>>(h, y, ln_w, ln_b, (size_t)(l*3+0)*DD, flag);

            wconv_kernel<<<wcg,256,0,stream>>>(ca_qkv_w, (size_t)l*3*DD*DD, ca_qkv_b, (size_t)l*3*DD,
                                               s1w, s1b, 3*DD*DD, 3*DD, flag);
            gemm_dual   <<<dim3(64,24),256,0,stream>>>(h, mem, s1w, s1b, qkv, DD, 3*DD);
            vt_kernel   <<<dim3(64,8,4),256,0,stream>>>(qkv, vt);
            flash_attn  <<<dim3(64,8),  256,0,stream>>>(qkv, vt, ao, 0);
            wconv_kernel<<<wcg,256,0,stream>>>(ca_out_w, (size_t)l*DD*DD, ca_out_b, (size_t)l*DD,
                                               s0w, s0b, DD*DD, DD, flag);
            gemm_bt<0,1><<<dim3(64,8), 256,0,stream>>>(ao, s0w, s0b, y, nullptr, h, DD, DD);
            ln_kernel   <<<dim3(MTOK), 256,0,stream>>>(h, y, ln_w, ln_b, (size_t)(l*3+1)*DD, flag);

            wconv_kernel<<<wcg,256,0,stream>>>(ff_w1, (size_t)l*DFFF*DD, ff_b1, (size_t)l*DFFF,
                                               s1w, s1b, DFFF*DD, DFFF, flag);
            gemm_bt<1,0><<<dim3(64,16),256,0,stream>>>(h, s1w, s1b, qkv, nullptr, nullptr, DD, DFFF);
            wconv_kernel<<<wcg,256,0,stream>>>(ff_w2, (size_t)l*DD*DFFF, ff_b2, (size_t)l*DD,
                                               s0w, s0b, DD*DFFF, DD, flag);
            gemm_bt<0,1><<<dim3(64,8), 256,0,stream>>>(qkv, s0w, s0b, y, nullptr, h, DFFF, DD);
            ln_kernel   <<<dim3(MTOK), 256,0,stream>>>(h, y, ln_w, ln_b, (size_t)(l*3+2)*DD, flag);
        }
        wconv_kernel<<<wcg,256,0,stream>>>(proj_w1, 0, proj_b1, 0, s1w, s1b, HIDD*DD, HIDD, flag);
        gemm_bt<0,0><<<dim3(64,4), 256,0,stream>>>(h, s1w, s1b, y, nullptr, nullptr, DD, HIDD);
        final_kernel<<<dim3(BB*LL),256,0,stream>>>(y, proj_w2, proj_b2, basis, d_out, flag);
    }
}